// Round 9
// baseline (577.297 us; speedup 1.0000x reference)
//
#include <hip/hip_runtime.h>
#include <hip/hip_bf16.h>
#include <stdint.h>

typedef unsigned short ushort_t;
typedef unsigned int uint_t;
typedef __attribute__((ext_vector_type(8))) short bfrag;   // 8 bf16 = 4 VGPR
typedef __attribute__((ext_vector_type(4))) float f32x4;

#define B_ 512
#define S_ 256
#define T_ 10
#define V_ 28
#define H_ 128

// ---- workspace layout (float element offsets) ----
#define XTD 0         // dec xg table [28][512]
#define XTG 14336     // enc xg gate-interleaved [2][28][128][4]
#define WTD 43008     // dec WhhT [128][512]
#define AWT 108544    // attn_WT [256][128]
#define OWT 141312    // out_WT [128][28]
#define PWT 144896    // projWT [256][128]
#define WPK 177664    // enc W bf16 K-extended frag pack, 262144 ushort
#define HFIN 308736
#define CFIN 439808
#define HDEC 570880
#define HS_BYTE_OFF (1226240ull * 4ull)
#define PREP_N 439808

__device__ __forceinline__ float fast_exp2(float x) { return __builtin_amdgcn_exp2f(x); }
__device__ __forceinline__ float fast_rcp(float x)  { return __builtin_amdgcn_rcpf(x); }
__device__ __forceinline__ float sigm(float x) {
    return fast_rcp(1.f + fast_exp2(-1.4426950408889634f * x));
}
__device__ __forceinline__ float tanh_(float x) {
    return 1.f - 2.f * fast_rcp(1.f + fast_exp2(2.8853900817779268f * x));
}
__device__ __forceinline__ ushort_t f2bf(float x) {
    uint_t u = __float_as_uint(x);
    return (ushort_t)((u + 0x7FFFu + ((u >> 16) & 1u)) >> 16);  // RNE
}
__device__ __forceinline__ float bflo(uint_t u) { return __uint_as_float(u << 16); }
__device__ __forceinline__ float bfhi(uint_t u) { return __uint_as_float(u & 0xFFFF0000u); }

// LDS-only barrier: drain LDS ops, sync, fence scheduler (rule #18).
__device__ __forceinline__ void lds_barrier() {
    asm volatile("s_waitcnt lgkmcnt(0)" ::: "memory");
    __builtin_amdgcn_s_barrier();
    __builtin_amdgcn_sched_barrier(0);
}

// ---------------- prep ----------------
__global__ __launch_bounds__(256) void prep_kernel(
    const float* __restrict__ embed,
    const float* __restrict__ Wih_f, const float* __restrict__ b_f,
    const float* __restrict__ Wih_b, const float* __restrict__ b_b,
    const float* __restrict__ Wih_d, const float* __restrict__ b_d,
    const float* __restrict__ Whh_f, const float* __restrict__ Whh_b,
    const float* __restrict__ Whh_d,
    const float* __restrict__ attn_W, const float* __restrict__ out_W,
    const float* __restrict__ proj_W,
    float* __restrict__ ws)
{
    int i = blockIdx.x * 256 + threadIdx.x;
    if (i < XTG) {                         // dec xg table: [v][j]
        int v = i >> 9, jj = i & 511;
        float acc = b_d[jj];
        #pragma unroll
        for (int e = 0; e < 32; ++e) acc = fmaf(embed[v * 32 + e], Wih_d[jj * 32 + e], acc);
        ws[XTD + i] = acc;
    } else if (i < WTD) {                  // enc xg gate-interleaved: [d][v][u][g]
        int r = i - XTG; int d = r / 14336; int rem = r % 14336;
        int v = rem >> 9, q = rem & 511;
        int uu = q >> 2, g = q & 3;
        int jj = g * 128 + uu;
        const float* Wih = d ? Wih_b : Wih_f;
        const float* bb  = d ? b_b   : b_f;
        float acc = bb[jj];
        #pragma unroll
        for (int e = 0; e < 32; ++e) acc = fmaf(embed[v * 32 + e], Wih[jj * 32 + e], acc);
        ws[XTG + r] = acc;
    } else if (i < AWT) {                  // dec WhhT[k][j]
        int r = i - WTD; int k = r >> 9, jj = r & 511;
        ws[WTD + r] = Whh_d[jj * 128 + k];
    } else if (i < OWT) {                  // attn_WT[k][u]
        int r = i - AWT; int k = r >> 7, uu = r & 127;
        ws[i] = attn_W[uu * 256 + k];
    } else if (i < PWT) {                  // out_WT[k][v]
        int r = i - OWT; int k = r / 28, v = r % 28;
        ws[i] = out_W[v * 128 + k];
    } else if (i < HFIN && i < WPK) {      // projWT[k][u]
        int r = i - PWT; int k = r >> 7, uu = r & 127;
        ws[i] = proj_W[uu * 256 + k];
    } else if (i < PREP_N) {               // enc weight pack, K-extended (k'<128 hi, k'>=128 lo)
        int i2 = i - WPK;
        int e  = i2 & 7;
        int ll = (i2 >> 3) & 63;
        int kt = (i2 >> 9) & 7;
        int ni = (i2 >> 12) & 3;
        int wv = (i2 >> 14) & 7;
        int d  = (i2 >> 17) & 1;
        int jj = (ni * 8 + wv) * 16 + (ll & 15);     // gate column (N)
        int kp = kt * 32 + ((ll >> 4) << 3) + e;     // extended K 0..255
        const float* Whh = d ? Whh_b : Whh_f;
        ushort_t ov;
        if (kp < 128) {
            ov = f2bf(Whh[jj * 128 + kp]);
        } else {
            float Wv = Whh[jj * 128 + kp - 128];
            ushort_t hi = f2bf(Wv);
            ov = f2bf(Wv - __uint_as_float((uint_t)hi << 16));
        }
        ((ushort_t*)(ws + WPK))[i2] = ov;
    }
}

// ---------------- encoder: ping-pong MFMA, 2 groups x 2 rows, 256 blocks, 8 waves ----------------
// K-extended bf16 split: [h_hi|h_lo] . [W_hi|W_lo] over K=256 -> 32 MFMA/wave/group-step.
// Phase P1: MFMA_A(t) || cell_B(t-1);  P2: MFMA_B(t) || cell_A(t).  1 barrier/group-step.
__global__ __launch_bounds__(512, 2) void enc_kernel(
    const int* __restrict__ src,
    const float* __restrict__ xtg_base,     // ws+XTG
    const ushort_t* __restrict__ wpk,       // ws+WPK
    float* __restrict__ hfin, float* __restrict__ cfin,
    ushort_t* __restrict__ hs)
{
    const int bx = blockIdx.x;
    const int dir = bx >> 7;
    const int b0 = (bx & 127) << 2;        // rows b0..b0+1 = group A, b0+2..b0+3 = group B
    const int tid = threadIdx.x;
    const int w = tid >> 6, l = tid & 63;
    const int lg = l >> 4, col = l & 15;
    const int u = (w << 4) + col;

    __shared__ ushort_t hbufA[2][2][256];          // [buf][row][K-ext swizzled]
    __shared__ ushort_t hbufB[2][2][256];
    __shared__ __align__(16) int tokl[256][4];     // [s][row]
    __shared__ __align__(16) float gA[4][2][128];  // [gate][row][u]
    __shared__ __align__(16) float gB[4][2][128];

    for (int i = tid; i < 1024; i += 512)
        tokl[i >> 2][i & 3] = src[(b0 + (i & 3)) * S_ + (i >> 2)];
    ((uint_t*)hbufA)[tid & 511] = 0u;   // 512 dwords each
    ((uint_t*)hbufB)[tid & 511] = 0u;

    const float* xtg = xtg_base + dir * 14336;

    // persistent B fragments: 4 N-tiles x 8 K-tiles = 128 regs (shared by both groups)
    bfrag bf[4][8];
    {
        const ushort_t* wb = wpk + (((size_t)dir * 8 + w) << 14) + l * 8;
        #pragma unroll
        for (int ni = 0; ni < 4; ++ni)
            #pragma unroll
            for (int kt = 0; kt < 8; ++kt)
                bf[ni][kt] = *reinterpret_cast<const bfrag*>(wb + ((ni * 8 + kt) << 9));
    }
    __syncthreads();

    // per-thread cell state (valid tid<256): thread -> (crow = tid>>7, cu = tid&127)
    const int crow = tid >> 7, cu = tid & 127;
    float cRegA = 0.f, hRegA = 0.f, cRegB = 0.f, hRegB = 0.f;

    f32x4 xgA0, xgA1, xgB0, xgB1;
    {
        int p0 = dir ? (S_ - 1) : 0;
        int4 tk = *reinterpret_cast<const int4*>(&tokl[p0][0]);
        xgA0 = *reinterpret_cast<const f32x4*>(xtg + ((size_t)tk.x << 9) + (u << 2));
        xgA1 = *reinterpret_cast<const f32x4*>(xtg + ((size_t)tk.y << 9) + (u << 2));
        xgB0 = *reinterpret_cast<const f32x4*>(xtg + ((size_t)tk.z << 9) + (u << 2));
        xgB1 = *reinterpret_cast<const f32x4*>(xtg + ((size_t)tk.w << 9) + (u << 2));
    }

    // persistent A fragments: zeroed once; only col<2 lanes overwrite (rows 2..15 pad = 0)
    const bfrag zf = {0, 0, 0, 0, 0, 0, 0, 0};
    bfrag af0 = zf, af1 = zf, af2 = zf, af3 = zf;
    bfrag af4 = zf, af5 = zf, af6 = zf, af7 = zf;
    const bool areader = (col < 2);

    #define MFMA32() \
        { \
        a0 = __builtin_amdgcn_mfma_f32_16x16x32_bf16(af0, bf[0][0], a0, 0, 0, 0); \
        a1 = __builtin_amdgcn_mfma_f32_16x16x32_bf16(af0, bf[1][0], a1, 0, 0, 0); \
        a2 = __builtin_amdgcn_mfma_f32_16x16x32_bf16(af0, bf[2][0], a2, 0, 0, 0); \
        a3 = __builtin_amdgcn_mfma_f32_16x16x32_bf16(af0, bf[3][0], a3, 0, 0, 0); \
        a0 = __builtin_amdgcn_mfma_f32_16x16x32_bf16(af1, bf[0][1], a0, 0, 0, 0); \
        a1 = __builtin_amdgcn_mfma_f32_16x16x32_bf16(af1, bf[1][1], a1, 0, 0, 0); \
        a2 = __builtin_amdgcn_mfma_f32_16x16x32_bf16(af1, bf[2][1], a2, 0, 0, 0); \
        a3 = __builtin_amdgcn_mfma_f32_16x16x32_bf16(af1, bf[3][1], a3, 0, 0, 0); \
        a0 = __builtin_amdgcn_mfma_f32_16x16x32_bf16(af2, bf[0][2], a0, 0, 0, 0); \
        a1 = __builtin_amdgcn_mfma_f32_16x16x32_bf16(af2, bf[1][2], a1, 0, 0, 0); \
        a2 = __builtin_amdgcn_mfma_f32_16x16x32_bf16(af2, bf[2][2], a2, 0, 0, 0); \
        a3 = __builtin_amdgcn_mfma_f32_16x16x32_bf16(af2, bf[3][2], a3, 0, 0, 0); \
        a0 = __builtin_amdgcn_mfma_f32_16x16x32_bf16(af3, bf[0][3], a0, 0, 0, 0); \
        a1 = __builtin_amdgcn_mfma_f32_16x16x32_bf16(af3, bf[1][3], a1, 0, 0, 0); \
        a2 = __builtin_amdgcn_mfma_f32_16x16x32_bf16(af3, bf[2][3], a2, 0, 0, 0); \
        a3 = __builtin_amdgcn_mfma_f32_16x16x32_bf16(af3, bf[3][3], a3, 0, 0, 0); \
        a0 = __builtin_amdgcn_mfma_f32_16x16x32_bf16(af4, bf[0][4], a0, 0, 0, 0); \
        a1 = __builtin_amdgcn_mfma_f32_16x16x32_bf16(af4, bf[1][4], a1, 0, 0, 0); \
        a2 = __builtin_amdgcn_mfma_f32_16x16x32_bf16(af4, bf[2][4], a2, 0, 0, 0); \
        a3 = __builtin_amdgcn_mfma_f32_16x16x32_bf16(af4, bf[3][4], a3, 0, 0, 0); \
        a0 = __builtin_amdgcn_mfma_f32_16x16x32_bf16(af5, bf[0][5], a0, 0, 0, 0); \
        a1 = __builtin_amdgcn_mfma_f32_16x16x32_bf16(af5, bf[1][5], a1, 0, 0, 0); \
        a2 = __builtin_amdgcn_mfma_f32_16x16x32_bf16(af5, bf[2][5], a2, 0, 0, 0); \
        a3 = __builtin_amdgcn_mfma_f32_16x16x32_bf16(af5, bf[3][5], a3, 0, 0, 0); \
        a0 = __builtin_amdgcn_mfma_f32_16x16x32_bf16(af6, bf[0][6], a0, 0, 0, 0); \
        a1 = __builtin_amdgcn_mfma_f32_16x16x32_bf16(af6, bf[1][6], a1, 0, 0, 0); \
        a2 = __builtin_amdgcn_mfma_f32_16x16x32_bf16(af6, bf[2][6], a2, 0, 0, 0); \
        a3 = __builtin_amdgcn_mfma_f32_16x16x32_bf16(af6, bf[3][6], a3, 0, 0, 0); \
        a0 = __builtin_amdgcn_mfma_f32_16x16x32_bf16(af7, bf[0][7], a0, 0, 0, 0); \
        a1 = __builtin_amdgcn_mfma_f32_16x16x32_bf16(af7, bf[1][7], a1, 0, 0, 0); \
        a2 = __builtin_amdgcn_mfma_f32_16x16x32_bf16(af7, bf[2][7], a2, 0, 0, 0); \
        a3 = __builtin_amdgcn_mfma_f32_16x16x32_bf16(af7, bf[3][7], a3, 0, 0, 0); \
        }

    #define AREAD(HB, buf) \
        if (areader) { \
            const ushort_t* hb = &HB[buf][col][0]; \
            const int swz = col << 3; \
            af0 = *reinterpret_cast<const bfrag*>(hb + ((  0 + (lg << 3)) ^ swz)); \
            af1 = *reinterpret_cast<const bfrag*>(hb + (( 32 + (lg << 3)) ^ swz)); \
            af2 = *reinterpret_cast<const bfrag*>(hb + (( 64 + (lg << 3)) ^ swz)); \
            af3 = *reinterpret_cast<const bfrag*>(hb + (( 96 + (lg << 3)) ^ swz)); \
            af4 = *reinterpret_cast<const bfrag*>(hb + ((128 + (lg << 3)) ^ swz)); \
            af5 = *reinterpret_cast<const bfrag*>(hb + ((160 + (lg << 3)) ^ swz)); \
            af6 = *reinterpret_cast<const bfrag*>(hb + ((192 + (lg << 3)) ^ swz)); \
            af7 = *reinterpret_cast<const bfrag*>(hb + ((224 + (lg << 3)) ^ swz)); \
        }

    #define GWRITE(G) \
        if (lg == 0) { \
            G[0][0][u] = a0[0]; G[0][1][u] = a0[1]; \
            G[1][0][u] = a1[0]; G[1][1][u] = a1[1]; \
            G[2][0][u] = a2[0]; G[2][1][u] = a2[1]; \
            G[3][0][u] = a3[0]; G[3][1][u] = a3[1]; \
        }

    #define CELL(G, HB, buf, CR, HR, BBASE, POS) \
        if (tid < 256) { \
            float gi = G[0][crow][cu], gf = G[1][crow][cu]; \
            float gg = G[2][crow][cu], go = G[3][crow][cu]; \
            float ii = sigm(gi), ff = sigm(gf), gG = tanh_(gg), oo = sigm(go); \
            CR = ff * CR + ii * gG; \
            float h = oo * tanh_(CR); \
            HR = h; \
            ushort_t hi = f2bf(h); \
            ushort_t lo = f2bf(h - __uint_as_float((uint_t)hi << 16)); \
            HB[buf][crow][cu ^ (crow << 3)] = hi; \
            HB[buf][crow][(128 + cu) ^ (crow << 3)] = lo; \
            hs[((size_t)(BBASE + crow) * S_ + (POS)) * 256 + dir * 128 + cu] = hi; \
        }

    for (int t = 0; t < S_; ++t) {
        const int cb = t & 1, nb = cb ^ 1;

        // ---- P1: MFMA_A(t) || cell_B(t-1) ----
        {
            AREAD(hbufA, cb)
            f32x4 a0 = {xgA0[0], xgA1[0], 0.f, 0.f};
            f32x4 a1 = {xgA0[1], xgA1[1], 0.f, 0.f};
            f32x4 a2 = {xgA0[2], xgA1[2], 0.f, 0.f};
            f32x4 a3 = {xgA0[3], xgA1[3], 0.f, 0.f};
            if (t + 1 < S_) {
                int pn = dir ? (S_ - 2 - t) : (t + 1);
                int2 tk = *reinterpret_cast<const int2*>(&tokl[pn][0]);
                xgA0 = *reinterpret_cast<const f32x4*>(xtg + ((size_t)tk.x << 9) + (u << 2));
                xgA1 = *reinterpret_cast<const f32x4*>(xtg + ((size_t)tk.y << 9) + (u << 2));
            }
            MFMA32()
            GWRITE(gA)
            if (t > 0) {
                int posB = dir ? (S_ - t) : (t - 1);
                CELL(gB, hbufB, cb, cRegB, hRegB, b0 + 2, posB)
            }
        }
        lds_barrier();

        // ---- P2: MFMA_B(t) || cell_A(t) ----
        {
            AREAD(hbufB, cb)
            f32x4 a0 = {xgB0[0], xgB1[0], 0.f, 0.f};
            f32x4 a1 = {xgB0[1], xgB1[1], 0.f, 0.f};
            f32x4 a2 = {xgB0[2], xgB1[2], 0.f, 0.f};
            f32x4 a3 = {xgB0[3], xgB1[3], 0.f, 0.f};
            if (t + 1 < S_) {
                int pn = dir ? (S_ - 2 - t) : (t + 1);
                int2 tk = *reinterpret_cast<const int2*>(&tokl[pn][2]);
                xgB0 = *reinterpret_cast<const f32x4*>(xtg + ((size_t)tk.x << 9) + (u << 2));
                xgB1 = *reinterpret_cast<const f32x4*>(xtg + ((size_t)tk.y << 9) + (u << 2));
            }
            MFMA32()
            GWRITE(gB)
            {
                int posA = dir ? (S_ - 1 - t) : t;
                CELL(gA, hbufA, nb, cRegA, hRegA, b0, posA)
            }
        }
        lds_barrier();
    }

    // epilogue: cell_B(S-1)
    {
        int posB = dir ? 0 : (S_ - 1);
        if (tid < 256) {
            float gi = gB[0][crow][cu], gf = gB[1][crow][cu];
            float gg = gB[2][crow][cu], go = gB[3][crow][cu];
            float ii = sigm(gi), ff = sigm(gf), gG = tanh_(gg), oo = sigm(go);
            cRegB = ff * cRegB + ii * gG;
            float h = oo * tanh_(cRegB);
            hRegB = h;
            hs[((size_t)(b0 + 2 + crow) * S_ + posB) * 256 + dir * 128 + cu] = f2bf(h);
        }
    }

    if (tid < 256) {
        hfin[dir * 65536 + (b0 + crow) * 128 + cu] = hRegA;
        cfin[dir * 65536 + (b0 + crow) * 128 + cu] = cRegA;
        hfin[dir * 65536 + (b0 + 2 + crow) * 128 + cu] = hRegB;
        cfin[dir * 65536 + (b0 + 2 + crow) * 128 + cu] = cRegB;
    }
    #undef MFMA32
    #undef AREAD
    #undef GWRITE
    #undef CELL
}

// ---------------- decoder LSTM only: 10 steps, store hdec[b][t][128] ----------------
__global__ __launch_bounds__(512, 1) void dec_lstm_kernel(
    const int* __restrict__ target,
    const float* __restrict__ xt_d,
    const float* __restrict__ WhhT_d,
    const float* __restrict__ hfin, const float* __restrict__ cfin,
    float* __restrict__ hdec)
{
    const int b0 = blockIdx.x * 2;
    const int tid = threadIdx.x;
    const int j = tid;

    __shared__ __align__(16) float h_lds[2][128];
    __shared__ __align__(16) float g_lds[2][512];

    float4 w4[32];
    #pragma unroll
    for (int kc = 0; kc < 32; ++kc) {
        w4[kc].x = WhhT_d[(kc * 4 + 0) * 512 + j];
        w4[kc].y = WhhT_d[(kc * 4 + 1) * 512 + j];
        w4[kc].z = WhhT_d[(kc * 4 + 2) * 512 + j];
        w4[kc].w = WhhT_d[(kc * 4 + 3) * 512 + j];
    }
    const int r1 = tid >> 7, u1 = tid & 127;
    float c = 0.f;
    if (tid < 256) {
        int b = b0 + r1;
        c = cfin[b * 128 + u1] + cfin[65536 + b * 128 + u1];
        h_lds[r1][u1] = hfin[b * 128 + u1] + hfin[65536 + b * 128 + u1];
    }
    __syncthreads();

    for (int t = 0; t < T_; ++t) {
        int tok0 = (t == 0) ? 0 : target[(b0 + 0) * T_ + t - 1];
        int tok1 = (t == 0) ? 0 : target[(b0 + 1) * T_ + t - 1];
        float a0 = xt_d[tok0 * 512 + j];
        float a1 = xt_d[tok1 * 512 + j];
        #pragma unroll
        for (int kc = 0; kc < 32; ++kc) {
            const float4 w = w4[kc];
            const float4 h0 = *reinterpret_cast<const float4*>(&h_lds[0][kc * 4]);
            const float4 h1 = *reinterpret_cast<const float4*>(&h_lds[1][kc * 4]);
            a0 = fmaf(h0.x, w.x, a0); a0 = fmaf(h0.y, w.y, a0); a0 = fmaf(h0.z, w.z, a0); a0 = fmaf(h0.w, w.w, a0);
            a1 = fmaf(h1.x, w.x, a1); a1 = fmaf(h1.y, w.y, a1); a1 = fmaf(h1.z, w.z, a1); a1 = fmaf(h1.w, w.w, a1);
        }
        g_lds[0][j] = a0; g_lds[1][j] = a1;
        __syncthreads();
        if (tid < 256) {
            float gi = g_lds[r1][u1], gf = g_lds[r1][u1 + 128];
            float gg = g_lds[r1][u1 + 256], go = g_lds[r1][u1 + 384];
            float ii = sigm(gi), ff = sigm(gf), g_ = tanh_(gg), oo = sigm(go);
            c = ff * c + ii * g_;
            float h = oo * tanh_(c);
            h_lds[r1][u1] = h;
            hdec[((size_t)(b0 + r1) * T_ + t) * 128 + u1] = h;
        }
        __syncthreads();
    }
}

// ---------------- attention + output, batched over all 10 t ----------------
__global__ __launch_bounds__(256, 2) void attn_kernel(
    const float* __restrict__ hdec,
    const float* __restrict__ projW, const float* __restrict__ proj_b,
    const float* __restrict__ projWT,
    const float* __restrict__ attn_WT, const float* __restrict__ attn_b,
    const float* __restrict__ out_WT, const float* __restrict__ out_b,
    const ushort_t* __restrict__ hs, float* __restrict__ out)
{
    const int b = blockIdx.x;
    const int tid = threadIdx.x;

    __shared__ __align__(16) float hd[1280];
    __shared__ __align__(16) float reg1[2560];
    __shared__ __align__(16) float sc[2560];
    __shared__ __align__(16) float part[10240];
    __shared__ __align__(16) float wsum[2560];

    const ushort_t* e = hs + (size_t)b * 65536;

    for (int i = tid; i < 1280; i += 256) hd[i] = hdec[(size_t)b * 1280 + i];
    __syncthreads();

    // phase 0: q[t][d] = sum_k hd[t][k] * projW[k][d]  (swizzle-stored)
    {
        float acc[10];
        #pragma unroll
        for (int t = 0; t < 10; ++t) acc[t] = 0.f;
        for (int k = 0; k < 128; ++k) {
            float pw = projW[k * 256 + tid];
            #pragma unroll
            for (int t = 0; t < 10; ++t) acc[t] = fmaf(hd[t * 128 + k], pw, acc[t]);
        }
        int swd = tid ^ ((((uint_t)tid >> 5) & 7) << 2);
        #pragma unroll
        for (int t = 0; t < 10; ++t) reg1[t * 256 + swd] = acc[t];
    }
    __syncthreads();

    // phase 1: scores[t][s] = e[s][:] . q[t][:]
    {
        const int w = tid >> 6, l = tid & 63;
        const int s3 = l >> 3, k8 = l & 7;
        for (int pass = 0; pass < 8; ++pass) {
            int s = w * 64 + pass * 8 + s3;
            const ushort_t* row = e + s * 256 + k8 * 32;
            uint4 e0 = *reinterpret_cast<const uint4*>(row);
            uint4 e1 = *reinterpret_cast<const uint4*>(row + 8);
            uint4 e2 = *reinterpret_cast<const uint4*>(row + 16);
            uint4 e3 = *reinterpret_cast<const uint4*>(row + 24);
            float acc[10];
            #pragma unroll
            for (int t = 0; t < 10; ++t) {
                const float* qb = &reg1[t * 256];
                float a = 0.f;
                #define QCH(i) (*reinterpret_cast<const float4*>(&qb[(k8 * 32 + (i) * 4) ^ (k8 << 2)]))
                #define DOT4(pa, pb, qv) { float4 q_ = (qv); \
                    a = fmaf(bflo(pa), q_.x, a); a = fmaf(bfhi(pa), q_.y, a); \
                    a = fmaf(bflo(pb), q_.z, a); a = fmaf(bfhi(pb), q_.w, a); }
                DOT4(e0.x, e0.y, QCH(0)); DOT4(e0.z, e0.w, QCH(1));
                DOT4(e1.x, e1.y, QCH(2)); DOT4(e1.z, e1.w, QCH(3));
                DOT4(e2.x, e2.y, QCH(4)); DOT4(e2.z, e2.w, QCH(5));
                DOT4(e3.x, e3.y, QCH(6)); DOT4(e3.z, e3.w, QCH(7));
                #undef QCH
                #undef DOT4
                acc[t] = a;
            }
            #pragma unroll
            for (int t = 0; t < 10; ++t) {
                acc[t] += __shfl_xor(acc[t], 1);
                acc[t] += __shfl_xor(acc[t], 2);
                acc[t] += __shfl_xor(acc[t], 4);
            }
            if (k8 == 0) {
                #pragma unroll
                for (int t = 0; t < 10; ++t) sc[t * 256 + s] = acc[t];
            }
        }
    }
    __syncthreads();

    // phase 2: softmax
    {
        const int w = tid >> 6, l = tid & 63;
        for (int t = w; t < 10; t += 4) {
            float4 sv = *reinterpret_cast<const float4*>(&sc[t * 256 + l * 4]);
            float m = fmaxf(fmaxf(sv.x, sv.y), fmaxf(sv.z, sv.w));
            #pragma unroll
            for (int o = 1; o < 64; o <<= 1) m = fmaxf(m, __shfl_xor(m, o));
            float e0 = fast_exp2((sv.x - m) * 1.4426950408889634f);
            float e1 = fast_exp2((sv.y - m) * 1.4426950408889634f);
            float e2 = fast_exp2((sv.z - m) * 1.4426950408889634f);
            float e3 = fast_exp2((sv.w - m) * 1.4426950408889634f);
            float ssum = e0 + e1 + e2 + e3;
            #pragma unroll
            for (int o = 1; o < 64; o <<= 1) ssum += __shfl_xor(ssum, o);
            float inv = fast_rcp(ssum);
            *reinterpret_cast<float4*>(&sc[t * 256 + l * 4]) =
                make_float4(e0 * inv, e1 * inv, e2 * inv, e3 * inv);
        }
    }
    __syncthreads();

    // phase 3: wsum partials
    {
        const int w = tid >> 6, l = tid & 63;
        float ax[10], ay[10], az[10], aw2[10];
        #pragma unroll
        for (int t = 0; t < 10; ++t) { ax[t] = 0.f; ay[t] = 0.f; az[t] = 0.f; aw2[t] = 0.f; }
        const ushort_t* col = e + l * 4;
        for (int s = w * 64; s < w * 64 + 64; ++s) {
            uint2 uu = *reinterpret_cast<const uint2*>(col + (size_t)s * 256);
            float v0 = bflo(uu.x), v1 = bfhi(uu.x), v2 = bflo(uu.y), v3 = bfhi(uu.y);
            #pragma unroll
            for (int t = 0; t < 10; ++t) {
                float awv = sc[t * 256 + s];
                ax[t] = fmaf(v0, awv, ax[t]); ay[t] = fmaf(v1, awv, ay[t]);
                az[t] = fmaf(v2, awv, az[t]); aw2[t] = fmaf(v3, awv, aw2[t]);
            }
        }
        #pragma unroll
        for (int t = 0; t < 10; ++t)
            *reinterpret_cast<float4*>(&part[(w * 10 + t) * 256 + l * 4]) =
                make_float4(ax[t], ay[t], az[t], aw2[t]);
    }
    __syncthreads();

    // phase 4: reduce partials
    for (int i = tid; i < 2560; i += 256)
        wsum[i] = part[i] + part[2560 + i] + part[5120 + i] + part[7680 + i];
    __syncthreads();

    // phase 5: ctx
    {
        const int u = tid & 127, th = tid >> 7;
        float acc[5];
        #pragma unroll
        for (int i = 0; i < 5; ++i) acc[i] = proj_b[u];
        for (int k = 0; k < 256; ++k) {
            float pw = projWT[k * 128 + u];
            #pragma unroll
            for (int i = 0; i < 5; ++i) acc[i] = fmaf(pw, wsum[(th * 5 + i) * 256 + k], acc[i]);
        }
        #pragma unroll
        for (int i = 0; i < 5; ++i) reg1[(th * 5 + i) * 128 + u] = acc[i];
    }
    __syncthreads();

    // phase 6: comb
    {
        const int u = tid & 127, th = tid >> 7;
        float acc[5];
        #pragma unroll
        for (int i = 0; i < 5; ++i) acc[i] = attn_b[u];
        for (int k = 0; k < 128; ++k) {
            float a1 = attn_WT[k * 128 + u];
            #pragma unroll
            for (int i = 0; i < 5; ++i) acc[i] = fmaf(a1, hd[(th * 5 + i) * 128 + k], acc[i]);
        }
        for (int k = 0; k < 128; ++k) {
            float a2 = attn_WT[(128 + k) * 128 + u];
            #pragma unroll
            for (int i = 0; i < 5; ++i) acc[i] = fmaf(a2, reg1[(th * 5 + i) * 128 + k], acc[i]);
        }
        #pragma unroll
        for (int i = 0; i < 5; ++i) reg1[1280 + (th * 5 + i) * 128 + u] = tanh_(acc[i]);
    }
    __syncthreads();

    // phase 7: logits
    for (int o = tid; o < 280; o += 256) {
        int t = o / 28, v = o - t * 28;
        float acc = out_b[v];
        #pragma unroll 4
        for (int k = 0; k < 128; ++k)
            acc = fmaf(out_WT[k * 28 + v], reg1[1280 + t * 128 + k], acc);
        out[(size_t)b * 280 + o] = acc;
    }
}

extern "C" void kernel_launch(void* const* d_in, const int* in_sizes, int n_in,
                              void* d_out, int out_size, void* d_ws, size_t ws_size,
                              hipStream_t stream) {
    const int* src      = (const int*)d_in[0];
    const int* target   = (const int*)d_in[1];
    const float* embed  = (const float*)d_in[2];
    const float* Wih_f  = (const float*)d_in[3];
    const float* Whh_f  = (const float*)d_in[4];
    const float* b_f    = (const float*)d_in[5];
    const float* Wih_b  = (const float*)d_in[6];
    const float* Whh_b  = (const float*)d_in[7];
    const float* b_b    = (const float*)d_in[8];
    const float* Wih_d  = (const float*)d_in[9];
    const float* Whh_d  = (const float*)d_in[10];
    const float* b_d    = (const float*)d_in[11];
    const float* proj_W = (const float*)d_in[12];
    const float* proj_b = (const float*)d_in[13];
    const float* attn_W = (const float*)d_in[14];
    const float* attn_b = (const float*)d_in[15];
    const float* out_W  = (const float*)d_in[16];
    const float* out_b  = (const float*)d_in[17];

    float* ws = (float*)d_ws;
    ushort_t* hs = (ushort_t*)((char*)d_ws + HS_BYTE_OFF);
    float* out = (float*)d_out;

    prep_kernel<<<(PREP_N + 255) / 256, 256, 0, stream>>>(
        embed, Wih_f, b_f, Wih_b, b_b, Wih_d, b_d,
        Whh_f, Whh_b, Whh_d, attn_W, out_W, proj_W, ws);

    enc_kernel<<<256, 512, 0, stream>>>(
        src, ws + XTG, (const ushort_t*)(ws + WPK),
        ws + HFIN, ws + CFIN, hs);

    dec_lstm_kernel<<<256, 512, 0, stream>>>(
        target, ws + XTD, ws + WTD, ws + HFIN, ws + CFIN, ws + HDEC);

    attn_kernel<<<512, 256, 0, stream>>>(
        ws + HDEC, proj_W, proj_b, ws + PWT, ws + AWT, attn_b,
        ws + OWT, out_b, hs, out);
}

// Round 10
// 430.057 us; speedup vs baseline: 1.3424x; 1.3424x over previous
//
#include <hip/hip_runtime.h>
#include <hip/hip_bf16.h>
#include <stdint.h>

typedef unsigned short ushort_t;
typedef unsigned int uint_t;
typedef __attribute__((ext_vector_type(8))) short bfrag;   // 8 bf16 = 4 VGPR
typedef __attribute__((ext_vector_type(4))) float f32x4;

#define B_ 512
#define S_ 256
#define T_ 10
#define V_ 28
#define H_ 128

// ---- workspace layout (float element offsets) ----
#define XTD 0         // dec xg table [28][512]
#define XTG 14336     // enc xg gate-interleaved [2][28][128][4]
#define WTD 43008     // dec WhhT [128][512]
#define AWT 108544    // attn_WT [256][128]
#define OWT 141312    // out_WT [128][28]
#define PWT 144896    // projWT [256][128]
#define WPK 177664    // enc W bf16 K-extended frag pack, 262144 ushort
#define HFIN 308736
#define CFIN 439808
#define HDEC 570880
#define HS_BYTE_OFF (1226240ull * 4ull)
#define PREP_N 439808

__device__ __forceinline__ float fast_exp2(float x) { return __builtin_amdgcn_exp2f(x); }
__device__ __forceinline__ float fast_rcp(float x)  { return __builtin_amdgcn_rcpf(x); }
__device__ __forceinline__ float sigm(float x) {
    return fast_rcp(1.f + fast_exp2(-1.4426950408889634f * x));
}
__device__ __forceinline__ float tanh_(float x) {
    return 1.f - 2.f * fast_rcp(1.f + fast_exp2(2.8853900817779268f * x));
}
__device__ __forceinline__ ushort_t f2bf(float x) {
    uint_t u = __float_as_uint(x);
    return (ushort_t)((u + 0x7FFFu + ((u >> 16) & 1u)) >> 16);  // RNE
}
__device__ __forceinline__ float bflo(uint_t u) { return __uint_as_float(u << 16); }
__device__ __forceinline__ float bfhi(uint_t u) { return __uint_as_float(u & 0xFFFF0000u); }

// LDS-only barrier: drain LDS ops, sync, fence scheduler (rule #18).
__device__ __forceinline__ void lds_barrier() {
    asm volatile("s_waitcnt lgkmcnt(0)" ::: "memory");
    __builtin_amdgcn_s_barrier();
    __builtin_amdgcn_sched_barrier(0);
}

// ---------------- prep (identical to round 9) ----------------
__global__ __launch_bounds__(256) void prep_kernel(
    const float* __restrict__ embed,
    const float* __restrict__ Wih_f, const float* __restrict__ b_f,
    const float* __restrict__ Wih_b, const float* __restrict__ b_b,
    const float* __restrict__ Wih_d, const float* __restrict__ b_d,
    const float* __restrict__ Whh_f, const float* __restrict__ Whh_b,
    const float* __restrict__ Whh_d,
    const float* __restrict__ attn_W, const float* __restrict__ out_W,
    const float* __restrict__ proj_W,
    float* __restrict__ ws)
{
    int i = blockIdx.x * 256 + threadIdx.x;
    if (i < XTG) {                         // dec xg table: [v][j]
        int v = i >> 9, jj = i & 511;
        float acc = b_d[jj];
        #pragma unroll
        for (int e = 0; e < 32; ++e) acc = fmaf(embed[v * 32 + e], Wih_d[jj * 32 + e], acc);
        ws[XTD + i] = acc;
    } else if (i < WTD) {                  // enc xg gate-interleaved: [d][v][u][g]
        int r = i - XTG; int d = r / 14336; int rem = r % 14336;
        int v = rem >> 9, q = rem & 511;
        int uu = q >> 2, g = q & 3;
        int jj = g * 128 + uu;
        const float* Wih = d ? Wih_b : Wih_f;
        const float* bb  = d ? b_b   : b_f;
        float acc = bb[jj];
        #pragma unroll
        for (int e = 0; e < 32; ++e) acc = fmaf(embed[v * 32 + e], Wih[jj * 32 + e], acc);
        ws[XTG + r] = acc;
    } else if (i < AWT) {                  // dec WhhT[k][j]
        int r = i - WTD; int k = r >> 9, jj = r & 511;
        ws[WTD + r] = Whh_d[jj * 128 + k];
    } else if (i < OWT) {                  // attn_WT[k][u]
        int r = i - AWT; int k = r >> 7, uu = r & 127;
        ws[i] = attn_W[uu * 256 + k];
    } else if (i < PWT) {                  // out_WT[k][v]
        int r = i - OWT; int k = r / 28, v = r % 28;
        ws[i] = out_W[v * 128 + k];
    } else if (i < WPK) {                  // projWT[k][u]
        int r = i - PWT; int k = r >> 7, uu = r & 127;
        ws[i] = proj_W[uu * 256 + k];
    } else if (i < PREP_N) {               // enc weight pack, K-extended (k'<128 hi, k'>=128 lo)
        int i2 = i - WPK;
        int e  = i2 & 7;
        int ll = (i2 >> 3) & 63;
        int kt = (i2 >> 9) & 7;
        int ni = (i2 >> 12) & 3;
        int wv = (i2 >> 14) & 7;
        int d  = (i2 >> 17) & 1;
        int jj = (ni * 8 + wv) * 16 + (ll & 15);     // gate column (N)
        int kp = kt * 32 + ((ll >> 4) << 3) + e;     // extended K 0..255
        const float* Whh = d ? Whh_b : Whh_f;
        ushort_t ov;
        if (kp < 128) {
            ov = f2bf(Whh[jj * 128 + kp]);
        } else {
            float Wv = Whh[jj * 128 + kp - 128];
            ushort_t hi = f2bf(Wv);
            ov = f2bf(Wv - __uint_as_float((uint_t)hi << 16));
        }
        ((ushort_t*)(ws + WPK))[i2] = ov;
    }
}

// ---------------- encoder: MFMA, rows at M={0,4,8,12}, in-lane cell, 1 barrier/step ----------------
// K-ext bf16 split over K=256 -> 32 MFMA/wave/step. C/D row = (lane>>4)*4+reg, so
// reg 0 of lane group lg holds M-row 4*lg = batch row lg: EVERY lane owns one cell's
// 4 gates in-register after MFMA. No g_lds, no gate redistribution, one barrier.
__global__ __launch_bounds__(512, 2) void enc_kernel(
    const int* __restrict__ src,
    const float* __restrict__ xtg_base,     // ws+XTG
    const ushort_t* __restrict__ wpk,       // ws+WPK
    float* __restrict__ hfin, float* __restrict__ cfin,
    ushort_t* __restrict__ hs)
{
    const int bx = blockIdx.x;
    const int dir = bx >> 7;
    const int b0 = (bx & 127) << 2;
    const int tid = threadIdx.x;
    const int w = tid >> 6, l = tid & 63;
    const int lg = l >> 4, col = l & 15;
    const int u = (w << 4) + col;          // 0..127: this lane's hidden unit
    const int row = lg;                    // this lane's batch row (cell owner)

    __shared__ ushort_t hb[2][4][256];             // [buf][row][swizzled K-ext]
    __shared__ __align__(16) int tokl[256][4];     // [s][row]

    for (int i = tid; i < 1024; i += 512)
        tokl[i >> 2][i & 3] = src[(b0 + (i & 3)) * S_ + (i >> 2)];
    ((uint_t*)hb)[tid] = 0u;               // zero both buffers: 1024 dwords
    ((uint_t*)hb)[tid + 512] = 0u;

    const float* xtg = xtg_base + dir * 14336;

    // persistent B fragments: 4 N-tiles x 8 K-tiles = 128 regs
    bfrag bf[4][8];
    {
        const ushort_t* wb = wpk + (((size_t)dir * 8 + w) << 14) + l * 8;
        #pragma unroll
        for (int ni = 0; ni < 4; ++ni)
            #pragma unroll
            for (int kt = 0; kt < 8; ++kt)
                bf[ni][kt] = *reinterpret_cast<const bfrag*>(wb + ((ni * 8 + kt) << 9));
    }
    __syncthreads();

    float c_reg = 0.f, h_reg = 0.f;

    f32x4 xgc;                              // this lane's 4 gate-bias terms for (row, u)
    {
        int p0 = dir ? (S_ - 1) : 0;
        xgc = *reinterpret_cast<const f32x4*>(xtg + ((size_t)tokl[p0][row] << 9) + (u << 2));
    }

    // A fragments: A row = lane&15; real rows at M = {0,4,8,12} -> lanes col&3==0 read row col>>2
    const bfrag zf = {0, 0, 0, 0, 0, 0, 0, 0};
    bfrag af0 = zf, af1 = zf, af2 = zf, af3 = zf;
    bfrag af4 = zf, af5 = zf, af6 = zf, af7 = zf;
    const bool ard = ((col & 3) == 0);
    const int ar = col >> 2;               // A-read row
    const int swz = ar << 3;

    for (int t = 0; t < S_; ++t) {
        const int cb = t & 1, nb = cb ^ 1;

        // acc init: reg 0 = xg for (row, u); regs 1..3 are padding rows (stay 0)
        f32x4 a0 = {xgc[0], 0.f, 0.f, 0.f};
        f32x4 a1 = {xgc[1], 0.f, 0.f, 0.f};
        f32x4 a2 = {xgc[2], 0.f, 0.f, 0.f};
        f32x4 a3 = {xgc[3], 0.f, 0.f, 0.f};

        // prefetch next step's xg (1 load/lane, consumed next iteration)
        if (t + 1 < S_) {
            int pn = dir ? (S_ - 2 - t) : (t + 1);
            xgc = *reinterpret_cast<const f32x4*>(xtg + ((size_t)tokl[pn][row] << 9) + (u << 2));
        }

        // masked A-frag reads: lanes col in {0,4,8,12} (16/wave), XOR-swizzled
        if (ard) {
            const ushort_t* hp = &hb[cb][ar][0];
            af0 = *reinterpret_cast<const bfrag*>(hp + ((  0 + (lg << 3)) ^ swz));
            af1 = *reinterpret_cast<const bfrag*>(hp + (( 32 + (lg << 3)) ^ swz));
            af2 = *reinterpret_cast<const bfrag*>(hp + (( 64 + (lg << 3)) ^ swz));
            af3 = *reinterpret_cast<const bfrag*>(hp + (( 96 + (lg << 3)) ^ swz));
            af4 = *reinterpret_cast<const bfrag*>(hp + ((128 + (lg << 3)) ^ swz));
            af5 = *reinterpret_cast<const bfrag*>(hp + ((160 + (lg << 3)) ^ swz));
            af6 = *reinterpret_cast<const bfrag*>(hp + ((192 + (lg << 3)) ^ swz));
            af7 = *reinterpret_cast<const bfrag*>(hp + ((224 + (lg << 3)) ^ swz));
        }

        #define KT1(AF, kt) { \
            a0 = __builtin_amdgcn_mfma_f32_16x16x32_bf16(AF, bf[0][kt], a0, 0, 0, 0); \
            a1 = __builtin_amdgcn_mfma_f32_16x16x32_bf16(AF, bf[1][kt], a1, 0, 0, 0); \
            a2 = __builtin_amdgcn_mfma_f32_16x16x32_bf16(AF, bf[2][kt], a2, 0, 0, 0); \
            a3 = __builtin_amdgcn_mfma_f32_16x16x32_bf16(AF, bf[3][kt], a3, 0, 0, 0); \
        }
        KT1(af0, 0) KT1(af1, 1) KT1(af2, 2) KT1(af3, 3)
        KT1(af4, 4) KT1(af5, 5) KT1(af6, 6) KT1(af7, 7)
        #undef KT1

        // cell: fully in-register, every lane owns one (row, u)
        {
            float gi = a0[0], gf = a1[0], gg = a2[0], go = a3[0];
            float ii = sigm(gi), ff = sigm(gf), gG = tanh_(gg), oo = sigm(go);
            c_reg = ff * c_reg + ii * gG;
            float h = oo * tanh_(c_reg);
            h_reg = h;
            ushort_t hi = f2bf(h);
            ushort_t lo = f2bf(h - __uint_as_float((uint_t)hi << 16));
            hb[nb][row][u ^ (row << 3)] = hi;
            hb[nb][row][(128 + u) ^ (row << 3)] = lo;
            int pos = dir ? (S_ - 1 - t) : t;
            hs[((size_t)(b0 + row) * S_ + pos) * 256 + dir * 128 + u] = hi;
        }
        lds_barrier();
    }

    hfin[dir * 65536 + (b0 + row) * 128 + u] = h_reg;
    cfin[dir * 65536 + (b0 + row) * 128 + u] = c_reg;
}

// ---------------- decoder LSTM only: 10 steps, store hdec[b][t][128] ----------------
__global__ __launch_bounds__(512, 1) void dec_lstm_kernel(
    const int* __restrict__ target,
    const float* __restrict__ xt_d,
    const float* __restrict__ WhhT_d,
    const float* __restrict__ hfin, const float* __restrict__ cfin,
    float* __restrict__ hdec)
{
    const int b0 = blockIdx.x * 2;
    const int tid = threadIdx.x;
    const int j = tid;

    __shared__ __align__(16) float h_lds[2][128];
    __shared__ __align__(16) float g_lds[2][512];

    float4 w4[32];
    #pragma unroll
    for (int kc = 0; kc < 32; ++kc) {
        w4[kc].x = WhhT_d[(kc * 4 + 0) * 512 + j];
        w4[kc].y = WhhT_d[(kc * 4 + 1) * 512 + j];
        w4[kc].z = WhhT_d[(kc * 4 + 2) * 512 + j];
        w4[kc].w = WhhT_d[(kc * 4 + 3) * 512 + j];
    }
    const int r1 = tid >> 7, u1 = tid & 127;
    float c = 0.f;
    if (tid < 256) {
        int b = b0 + r1;
        c = cfin[b * 128 + u1] + cfin[65536 + b * 128 + u1];
        h_lds[r1][u1] = hfin[b * 128 + u1] + hfin[65536 + b * 128 + u1];
    }
    __syncthreads();

    for (int t = 0; t < T_; ++t) {
        int tok0 = (t == 0) ? 0 : target[(b0 + 0) * T_ + t - 1];
        int tok1 = (t == 0) ? 0 : target[(b0 + 1) * T_ + t - 1];
        float a0 = xt_d[tok0 * 512 + j];
        float a1 = xt_d[tok1 * 512 + j];
        #pragma unroll
        for (int kc = 0; kc < 32; ++kc) {
            const float4 w = w4[kc];
            const float4 h0 = *reinterpret_cast<const float4*>(&h_lds[0][kc * 4]);
            const float4 h1 = *reinterpret_cast<const float4*>(&h_lds[1][kc * 4]);
            a0 = fmaf(h0.x, w.x, a0); a0 = fmaf(h0.y, w.y, a0); a0 = fmaf(h0.z, w.z, a0); a0 = fmaf(h0.w, w.w, a0);
            a1 = fmaf(h1.x, w.x, a1); a1 = fmaf(h1.y, w.y, a1); a1 = fmaf(h1.z, w.z, a1); a1 = fmaf(h1.w, w.w, a1);
        }
        g_lds[0][j] = a0; g_lds[1][j] = a1;
        __syncthreads();
        if (tid < 256) {
            float gi = g_lds[r1][u1], gf = g_lds[r1][u1 + 128];
            float gg = g_lds[r1][u1 + 256], go = g_lds[r1][u1 + 384];
            float ii = sigm(gi), ff = sigm(gf), g_ = tanh_(gg), oo = sigm(go);
            c = ff * c + ii * g_;
            float h = oo * tanh_(c);
            h_lds[r1][u1] = h;
            hdec[((size_t)(b0 + r1) * T_ + t) * 128 + u1] = h;
        }
        __syncthreads();
    }
}

// ---------------- attention + output, batched over all 10 t ----------------
__global__ __launch_bounds__(256, 2) void attn_kernel(
    const float* __restrict__ hdec,
    const float* __restrict__ projW, const float* __restrict__ proj_b,
    const float* __restrict__ projWT,
    const float* __restrict__ attn_WT, const float* __restrict__ attn_b,
    const float* __restrict__ out_WT, const float* __restrict__ out_b,
    const ushort_t* __restrict__ hs, float* __restrict__ out)
{
    const int b = blockIdx.x;
    const int tid = threadIdx.x;

    __shared__ __align__(16) float hd[1280];
    __shared__ __align__(16) float reg1[2560];
    __shared__ __align__(16) float sc[2560];
    __shared__ __align__(16) float part[10240];
    __shared__ __align__(16) float wsum[2560];

    const ushort_t* e = hs + (size_t)b * 65536;

    for (int i = tid; i < 1280; i += 256) hd[i] = hdec[(size_t)b * 1280 + i];
    __syncthreads();

    // phase 0: q[t][d] = sum_k hd[t][k] * projW[k][d]  (swizzle-stored)
    {
        float acc[10];
        #pragma unroll
        for (int t = 0; t < 10; ++t) acc[t] = 0.f;
        for (int k = 0; k < 128; ++k) {
            float pw = projW[k * 256 + tid];
            #pragma unroll
            for (int t = 0; t < 10; ++t) acc[t] = fmaf(hd[t * 128 + k], pw, acc[t]);
        }
        int swd = tid ^ ((((uint_t)tid >> 5) & 7) << 2);
        #pragma unroll
        for (int t = 0; t < 10; ++t) reg1[t * 256 + swd] = acc[t];
    }
    __syncthreads();

    // phase 1: scores[t][s] = e[s][:] . q[t][:]
    {
        const int w = tid >> 6, l = tid & 63;
        const int s3 = l >> 3, k8 = l & 7;
        for (int pass = 0; pass < 8; ++pass) {
            int s = w * 64 + pass * 8 + s3;
            const ushort_t* row = e + s * 256 + k8 * 32;
            uint4 e0 = *reinterpret_cast<const uint4*>(row);
            uint4 e1 = *reinterpret_cast<const uint4*>(row + 8);
            uint4 e2 = *reinterpret_cast<const uint4*>(row + 16);
            uint4 e3 = *reinterpret_cast<const uint4*>(row + 24);
            float acc[10];
            #pragma unroll
            for (int t = 0; t < 10; ++t) {
                const float* qb = &reg1[t * 256];
                float a = 0.f;
                #define QCH(i) (*reinterpret_cast<const float4*>(&qb[(k8 * 32 + (i) * 4) ^ (k8 << 2)]))
                #define DOT4(pa, pb, qv) { float4 q_ = (qv); \
                    a = fmaf(bflo(pa), q_.x, a); a = fmaf(bfhi(pa), q_.y, a); \
                    a = fmaf(bflo(pb), q_.z, a); a = fmaf(bfhi(pb), q_.w, a); }
                DOT4(e0.x, e0.y, QCH(0)); DOT4(e0.z, e0.w, QCH(1));
                DOT4(e1.x, e1.y, QCH(2)); DOT4(e1.z, e1.w, QCH(3));
                DOT4(e2.x, e2.y, QCH(4)); DOT4(e2.z, e2.w, QCH(5));
                DOT4(e3.x, e3.y, QCH(6)); DOT4(e3.z, e3.w, QCH(7));
                #undef QCH
                #undef DOT4
                acc[t] = a;
            }
            #pragma unroll
            for (int t = 0; t < 10; ++t) {
                acc[t] += __shfl_xor(acc[t], 1);
                acc[t] += __shfl_xor(acc[t], 2);
                acc[t] += __shfl_xor(acc[t], 4);
            }
            if (k8 == 0) {
                #pragma unroll
                for (int t = 0; t < 10; ++t) sc[t * 256 + s] = acc[t];
            }
        }
    }
    __syncthreads();

    // phase 2: softmax
    {
        const int w = tid >> 6, l = tid & 63;
        for (int t = w; t < 10; t += 4) {
            float4 sv = *reinterpret_cast<const float4*>(&sc[t * 256 + l * 4]);
            float m = fmaxf(fmaxf(sv.x, sv.y), fmaxf(sv.z, sv.w));
            #pragma unroll
            for (int o = 1; o < 64; o <<= 1) m = fmaxf(m, __shfl_xor(m, o));
            float e0 = fast_exp2((sv.x - m) * 1.4426950408889634f);
            float e1 = fast_exp2((sv.y - m) * 1.4426950408889634f);
            float e2 = fast_exp2((sv.z - m) * 1.4426950408889634f);
            float e3 = fast_exp2((sv.w - m) * 1.4426950408889634f);
            float ssum = e0 + e1 + e2 + e3;
            #pragma unroll
            for (int o = 1; o < 64; o <<= 1) ssum += __shfl_xor(ssum, o);
            float inv = fast_rcp(ssum);
            *reinterpret_cast<float4*>(&sc[t * 256 + l * 4]) =
                make_float4(e0 * inv, e1 * inv, e2 * inv, e3 * inv);
        }
    }
    __syncthreads();

    // phase 3: wsum partials
    {
        const int w = tid >> 6, l = tid & 63;
        float ax[10], ay[10], az[10], aw2[10];
        #pragma unroll
        for (int t = 0; t < 10; ++t) { ax[t] = 0.f; ay[t] = 0.f; az[t] = 0.f; aw2[t] = 0.f; }
        const ushort_t* col = e + l * 4;
        for (int s = w * 64; s < w * 64 + 64; ++s) {
            uint2 uu = *reinterpret_cast<const uint2*>(col + (size_t)s * 256);
            float v0 = bflo(uu.x), v1 = bfhi(uu.x), v2 = bflo(uu.y), v3 = bfhi(uu.y);
            #pragma unroll
            for (int t = 0; t < 10; ++t) {
                float awv = sc[t * 256 + s];
                ax[t] = fmaf(v0, awv, ax[t]); ay[t] = fmaf(v1, awv, ay[t]);
                az[t] = fmaf(v2, awv, az[t]); aw2[t] = fmaf(v3, awv, aw2[t]);
            }
        }
        #pragma unroll
        for (int t = 0; t < 10; ++t)
            *reinterpret_cast<float4*>(&part[(w * 10 + t) * 256 + l * 4]) =
                make_float4(ax[t], ay[t], az[t], aw2[t]);
    }
    __syncthreads();

    // phase 4: reduce partials
    for (int i = tid; i < 2560; i += 256)
        wsum[i] = part[i] + part[2560 + i] + part[5120 + i] + part[7680 + i];
    __syncthreads();

    // phase 5: ctx
    {
        const int u = tid & 127, th = tid >> 7;
        float acc[5];
        #pragma unroll
        for (int i = 0; i < 5; ++i) acc[i] = proj_b[u];
        for (int k = 0; k < 256; ++k) {
            float pw = projWT[k * 128 + u];
            #pragma unroll
            for (int i = 0; i < 5; ++i) acc[i] = fmaf(pw, wsum[(th * 5 + i) * 256 + k], acc[i]);
        }
        #pragma unroll
        for (int i = 0; i < 5; ++i) reg1[(th * 5 + i) * 128 + u] = acc[i];
    }
    __syncthreads();

    // phase 6: comb
    {
        const int u = tid & 127, th = tid >> 7;
        float acc[5];
        #pragma unroll
        for (int i = 0; i < 5; ++i) acc[i] = attn_b[u];
        for (int k = 0; k < 128; ++k) {
            float a1 = attn_WT[k * 128 + u];
            #pragma unroll
            for (int i = 0; i < 5; ++i) acc[i] = fmaf(a1, hd[(th * 5 + i) * 128 + k], acc[i]);
        }
        for (int k = 0; k < 128; ++k) {
            float a2 = attn_WT[(128 + k) * 128 + u];
            #pragma unroll
            for (int i = 0; i < 5; ++i) acc[i] = fmaf(a2, reg1[(th * 5 + i) * 128 + k], acc[i]);
        }
        #pragma unroll
        for (int i = 0; i < 5; ++i) reg1[1280 + (th * 5 + i) * 128 + u] = tanh_(acc[i]);
    }
    __syncthreads();

    // phase 7: logits
    for (int o = tid; o < 280; o += 256) {
        int t = o / 28, v = o - t * 28;
        float acc = out_b[v];
        #pragma unroll 4
        for (int k = 0; k < 128; ++k)
            acc = fmaf(out_WT[k * 28 + v], reg1[1280 + t * 128 + k], acc);
        out[(size_t)b * 280 + o] = acc;
    }
}

extern "C" void kernel_launch(void* const* d_in, const int* in_sizes, int n_in,
                              void* d_out, int out_size, void* d_ws, size_t ws_size,
                              hipStream_t stream) {
    const int* src      = (const int*)d_in[0];
    const int* target   = (const int*)d_in[1];
    const float* embed  = (const float*)d_in[2];
    const float* Wih_f  = (const float*)d_in[3];
    const float* Whh_f  = (const float*)d_in[4];
    const float* b_f    = (const float*)d_in[5];
    const float* Wih_b  = (const float*)d_in[6];
    const float* Whh_b  = (const float*)d_in[7];
    const float* b_b    = (const float*)d_in[8];
    const float* Wih_d  = (const float*)d_in[9];
    const float* Whh_d  = (const float*)d_in[10];
    const float* b_d    = (const float*)d_in[11];
    const float* proj_W = (const float*)d_in[12];
    const float* proj_b = (const float*)d_in[13];
    const float* attn_W = (const float*)d_in[14];
    const float* attn_b = (const float*)d_in[15];
    const float* out_W  = (const float*)d_in[16];
    const float* out_b  = (const float*)d_in[17];

    float* ws = (float*)d_ws;
    ushort_t* hs = (ushort_t*)((char*)d_ws + HS_BYTE_OFF);
    float* out = (float*)d_out;

    prep_kernel<<<(PREP_N + 255) / 256, 256, 0, stream>>>(
        embed, Wih_f, b_f, Wih_b, b_b, Wih_d, b_d,
        Whh_f, Whh_b, Whh_d, attn_W, out_W, proj_W, ws);

    enc_kernel<<<256, 512, 0, stream>>>(
        src, ws + XTG, (const ushort_t*)(ws + WPK),
        ws + HFIN, ws + CFIN, hs);

    dec_lstm_kernel<<<256, 512, 0, stream>>>(
        target, ws + XTD, ws + WTD, ws + HFIN, ws + CFIN, ws + HDEC);

    attn_kernel<<<512, 256, 0, stream>>>(
        ws + HDEC, proj_W, proj_b, ws + PWT, ws + AWT, attn_b,
        ws + OWT, out_b, hs, out);
}

// Round 11
// 347.531 us; speedup vs baseline: 1.6611x; 1.2375x over previous
//
#include <hip/hip_runtime.h>
#include <hip/hip_bf16.h>
#include <stdint.h>

typedef unsigned short ushort_t;
typedef unsigned int uint_t;
typedef __attribute__((ext_vector_type(8))) short bfrag;   // 8 bf16 = 4 VGPR
typedef __attribute__((ext_vector_type(4))) float f32x4;

#define B_ 512
#define S_ 256
#define T_ 10
#define V_ 28
#define H_ 128

// ---- workspace layout (float element offsets) ----
#define XTD 0         // dec xg table [28][512]
#define XTG 14336     // enc xg gate-interleaved [2][28][128][4]
#define WTD 43008     // dec WhhT [128][512]
#define AWT 108544    // attn_WT [256][128]
#define OWT 141312    // out_WT [128][28]
#define PWT 144896    // projWT [256][128]
#define WPK 177664    // enc W_hi bf16 frag pack, 131072 ushort (K=128)
#define HFIN 308736
#define CFIN 439808
#define HDEC 570880
#define HS_BYTE_OFF (1226240ull * 4ull)
#define PREP_N 308736

__device__ __forceinline__ float fast_exp2(float x) { return __builtin_amdgcn_exp2f(x); }
__device__ __forceinline__ float fast_rcp(float x)  { return __builtin_amdgcn_rcpf(x); }
__device__ __forceinline__ float sigm(float x) {
    return fast_rcp(1.f + fast_exp2(-1.4426950408889634f * x));
}
__device__ __forceinline__ float tanh_(float x) {
    return 1.f - 2.f * fast_rcp(1.f + fast_exp2(2.8853900817779268f * x));
}
__device__ __forceinline__ ushort_t f2bf(float x) {
    uint_t u = __float_as_uint(x);
    return (ushort_t)((u + 0x7FFFu + ((u >> 16) & 1u)) >> 16);  // RNE
}
__device__ __forceinline__ float bflo(uint_t u) { return __uint_as_float(u << 16); }
__device__ __forceinline__ float bfhi(uint_t u) { return __uint_as_float(u & 0xFFFF0000u); }

// LDS-only barrier: drain LDS ops, sync, fence scheduler (rule #18).
__device__ __forceinline__ void lds_barrier() {
    asm volatile("s_waitcnt lgkmcnt(0)" ::: "memory");
    __builtin_amdgcn_s_barrier();
    __builtin_amdgcn_sched_barrier(0);
}

// ---------------- prep ----------------
__global__ __launch_bounds__(256) void prep_kernel(
    const float* __restrict__ embed,
    const float* __restrict__ Wih_f, const float* __restrict__ b_f,
    const float* __restrict__ Wih_b, const float* __restrict__ b_b,
    const float* __restrict__ Wih_d, const float* __restrict__ b_d,
    const float* __restrict__ Whh_f, const float* __restrict__ Whh_b,
    const float* __restrict__ Whh_d,
    const float* __restrict__ attn_W, const float* __restrict__ out_W,
    const float* __restrict__ proj_W,
    float* __restrict__ ws)
{
    int i = blockIdx.x * 256 + threadIdx.x;
    if (i < XTG) {                         // dec xg table: [v][j]
        int v = i >> 9, jj = i & 511;
        float acc = b_d[jj];
        #pragma unroll
        for (int e = 0; e < 32; ++e) acc = fmaf(embed[v * 32 + e], Wih_d[jj * 32 + e], acc);
        ws[XTD + i] = acc;
    } else if (i < WTD) {                  // enc xg gate-interleaved: [d][v][u][g]
        int r = i - XTG; int d = r / 14336; int rem = r % 14336;
        int v = rem >> 9, q = rem & 511;
        int uu = q >> 2, g = q & 3;
        int jj = g * 128 + uu;
        const float* Wih = d ? Wih_b : Wih_f;
        const float* bb  = d ? b_b   : b_f;
        float acc = bb[jj];
        #pragma unroll
        for (int e = 0; e < 32; ++e) acc = fmaf(embed[v * 32 + e], Wih[jj * 32 + e], acc);
        ws[XTG + r] = acc;
    } else if (i < AWT) {                  // dec WhhT[k][j]
        int r = i - WTD; int k = r >> 9, jj = r & 511;
        ws[WTD + r] = Whh_d[jj * 128 + k];
    } else if (i < OWT) {                  // attn_WT[k][u]
        int r = i - AWT; int k = r >> 7, uu = r & 127;
        ws[i] = attn_W[uu * 256 + k];
    } else if (i < PWT) {                  // out_WT[k][v]
        int r = i - OWT; int k = r / 28, v = r % 28;
        ws[i] = out_W[v * 128 + k];
    } else if (i < WPK) {                  // projWT[k][u]
        int r = i - PWT; int k = r >> 7, uu = r & 127;
        ws[i] = proj_W[uu * 256 + k];
    } else if (i < PREP_N) {               // enc W_hi frag pack, K=128 (pure bf16 hi)
        int i2 = (i - WPK) * 2;            // 2 ushorts per thread
        #pragma unroll
        for (int p = 0; p < 2; ++p, ++i2) {
            int e  = i2 & 7;
            int ll = (i2 >> 3) & 63;
            int kt = (i2 >> 9) & 3;
            int ni = (i2 >> 11) & 3;
            int wv = (i2 >> 13) & 7;
            int d  = (i2 >> 16) & 1;
            int jj = (ni * 8 + wv) * 16 + (ll & 15);   // gate column (N)
            int kp = kt * 32 + ((ll >> 4) << 3) + e;   // K index 0..127
            const float* Whh = d ? Whh_b : Whh_f;
            ((ushort_t*)(ws + WPK))[i2] = f2bf(Whh[jj * 128 + kp]);
        }
    }
}

// ---------------- encoder: MFMA K=128 bf16, rows at M={0,4,8,12}, in-lane cell ----------------
// 16 MFMA/wave/step (MFMA floor 621 cyc/SIMD). hb row stride 144 ushorts (288B) ->
// rows on banks {0,8,16,24}: cell-writes conflict-free, A-reads <=2-way (free).
__global__ __launch_bounds__(512, 2) void enc_kernel(
    const int* __restrict__ src,
    const float* __restrict__ xtg_base,     // ws+XTG
    const ushort_t* __restrict__ wpk,       // ws+WPK
    float* __restrict__ hfin, float* __restrict__ cfin,
    ushort_t* __restrict__ hs)
{
    const int bx = blockIdx.x;
    const int dir = bx >> 7;
    const int b0 = (bx & 127) << 2;
    const int tid = threadIdx.x;
    const int w = tid >> 6, l = tid & 63;
    const int lg = l >> 4, col = l & 15;
    const int u = (w << 4) + col;          // 0..127: this lane's hidden unit
    const int row = lg;                    // this lane's batch row (cell owner)

    __shared__ __align__(16) ushort_t hb[2][4][144];   // [buf][row][swizzled u], stride-padded
    __shared__ __align__(16) int tokl[256][4];         // [s][row]

    for (int i = tid; i < 1024; i += 512)
        tokl[i >> 2][i & 3] = src[(b0 + (i & 3)) * S_ + (i >> 2)];
    for (int i = tid; i < 576; i += 512) ((uint_t*)hb)[i] = 0u;

    const float* xtg = xtg_base + dir * 14336;

    // persistent B fragments: 4 N-tiles x 4 K-tiles = 64 regs
    bfrag bf[4][4];
    {
        const ushort_t* wb = wpk + (((size_t)dir * 8 + w) << 13) + l * 8;
        #pragma unroll
        for (int ni = 0; ni < 4; ++ni)
            #pragma unroll
            for (int kt = 0; kt < 4; ++kt)
                bf[ni][kt] = *reinterpret_cast<const bfrag*>(wb + ((ni * 4 + kt) << 9));
    }
    __syncthreads();

    float c_reg = 0.f, h_reg = 0.f;

    f32x4 xgc;                              // this lane's 4 gate-bias terms for (row, u)
    {
        int p0 = dir ? (S_ - 1) : 0;
        xgc = *reinterpret_cast<const f32x4*>(xtg + ((size_t)tokl[p0][row] << 9) + (u << 2));
    }

    // A fragments: A row = lane&15; real rows at M = {0,4,8,12}
    const bfrag zf = {0, 0, 0, 0, 0, 0, 0, 0};
    bfrag af0 = zf, af1 = zf, af2 = zf, af3 = zf;
    const bool ard = ((col & 3) == 0);
    const int ar = col >> 2;               // A-read row
    const int swz = ar << 3;

    for (int t = 0; t < S_; ++t) {
        const int cb = t & 1, nb = cb ^ 1;

        // acc init: reg 0 = xg for (row, u); regs 1..3 are padding rows (stay 0)
        f32x4 a0 = {xgc[0], 0.f, 0.f, 0.f};
        f32x4 a1 = {xgc[1], 0.f, 0.f, 0.f};
        f32x4 a2 = {xgc[2], 0.f, 0.f, 0.f};
        f32x4 a3 = {xgc[3], 0.f, 0.f, 0.f};

        // prefetch next step's xg (1 load/lane, consumed next iteration)
        if (t + 1 < S_) {
            int pn = dir ? (S_ - 2 - t) : (t + 1);
            xgc = *reinterpret_cast<const f32x4*>(xtg + ((size_t)tokl[pn][row] << 9) + (u << 2));
        }

        // masked A-frag reads: lanes col in {0,4,8,12}, XOR-swizzled, <=2-way banks
        if (ard) {
            const ushort_t* hp = &hb[cb][ar][0];
            af0 = *reinterpret_cast<const bfrag*>(hp + ((  0 + (lg << 3)) ^ swz));
            af1 = *reinterpret_cast<const bfrag*>(hp + (( 32 + (lg << 3)) ^ swz));
            af2 = *reinterpret_cast<const bfrag*>(hp + (( 64 + (lg << 3)) ^ swz));
            af3 = *reinterpret_cast<const bfrag*>(hp + (( 96 + (lg << 3)) ^ swz));
        }

        #define KT1(AF, kt) { \
            a0 = __builtin_amdgcn_mfma_f32_16x16x32_bf16(AF, bf[0][kt], a0, 0, 0, 0); \
            a1 = __builtin_amdgcn_mfma_f32_16x16x32_bf16(AF, bf[1][kt], a1, 0, 0, 0); \
            a2 = __builtin_amdgcn_mfma_f32_16x16x32_bf16(AF, bf[2][kt], a2, 0, 0, 0); \
            a3 = __builtin_amdgcn_mfma_f32_16x16x32_bf16(AF, bf[3][kt], a3, 0, 0, 0); \
        }
        KT1(af0, 0) KT1(af1, 1) KT1(af2, 2) KT1(af3, 3)
        #undef KT1

        // cell: fully in-register, every lane owns one (row, u)
        {
            float gi = a0[0], gf = a1[0], gg = a2[0], go = a3[0];
            float ii = sigm(gi), ff = sigm(gf), gG = tanh_(gg), oo = sigm(go);
            c_reg = ff * c_reg + ii * gG;
            float h = oo * tanh_(c_reg);
            h_reg = h;
            ushort_t hi = f2bf(h);
            hb[nb][row][u ^ (row << 3)] = hi;
            int pos = dir ? (S_ - 1 - t) : t;
            hs[((size_t)(b0 + row) * S_ + pos) * 256 + dir * 128 + u] = hi;
        }
        lds_barrier();
    }

    hfin[dir * 65536 + (b0 + row) * 128 + u] = h_reg;
    cfin[dir * 65536 + (b0 + row) * 128 + u] = c_reg;
}

// ---------------- decoder LSTM only: 10 steps, store hdec[b][t][128] ----------------
__global__ __launch_bounds__(512, 1) void dec_lstm_kernel(
    const int* __restrict__ target,
    const float* __restrict__ xt_d,
    const float* __restrict__ WhhT_d,
    const float* __restrict__ hfin, const float* __restrict__ cfin,
    float* __restrict__ hdec)
{
    const int b0 = blockIdx.x * 2;
    const int tid = threadIdx.x;
    const int j = tid;

    __shared__ __align__(16) float h_lds[2][128];
    __shared__ __align__(16) float g_lds[2][512];

    float4 w4[32];
    #pragma unroll
    for (int kc = 0; kc < 32; ++kc) {
        w4[kc].x = WhhT_d[(kc * 4 + 0) * 512 + j];
        w4[kc].y = WhhT_d[(kc * 4 + 1) * 512 + j];
        w4[kc].z = WhhT_d[(kc * 4 + 2) * 512 + j];
        w4[kc].w = WhhT_d[(kc * 4 + 3) * 512 + j];
    }
    const int r1 = tid >> 7, u1 = tid & 127;
    float c = 0.f;
    if (tid < 256) {
        int b = b0 + r1;
        c = cfin[b * 128 + u1] + cfin[65536 + b * 128 + u1];
        h_lds[r1][u1] = hfin[b * 128 + u1] + hfin[65536 + b * 128 + u1];
    }
    __syncthreads();

    for (int t = 0; t < T_; ++t) {
        int tok0 = (t == 0) ? 0 : target[(b0 + 0) * T_ + t - 1];
        int tok1 = (t == 0) ? 0 : target[(b0 + 1) * T_ + t - 1];
        float a0 = xt_d[tok0 * 512 + j];
        float a1 = xt_d[tok1 * 512 + j];
        #pragma unroll
        for (int kc = 0; kc < 32; ++kc) {
            const float4 w = w4[kc];
            const float4 h0 = *reinterpret_cast<const float4*>(&h_lds[0][kc * 4]);
            const float4 h1 = *reinterpret_cast<const float4*>(&h_lds[1][kc * 4]);
            a0 = fmaf(h0.x, w.x, a0); a0 = fmaf(h0.y, w.y, a0); a0 = fmaf(h0.z, w.z, a0); a0 = fmaf(h0.w, w.w, a0);
            a1 = fmaf(h1.x, w.x, a1); a1 = fmaf(h1.y, w.y, a1); a1 = fmaf(h1.z, w.z, a1); a1 = fmaf(h1.w, w.w, a1);
        }
        g_lds[0][j] = a0; g_lds[1][j] = a1;
        __syncthreads();
        if (tid < 256) {
            float gi = g_lds[r1][u1], gf = g_lds[r1][u1 + 128];
            float gg = g_lds[r1][u1 + 256], go = g_lds[r1][u1 + 384];
            float ii = sigm(gi), ff = sigm(gf), g_ = tanh_(gg), oo = sigm(go);
            c = ff * c + ii * g_;
            float h = oo * tanh_(c);
            h_lds[r1][u1] = h;
            hdec[((size_t)(b0 + r1) * T_ + t) * 128 + u1] = h;
        }
        __syncthreads();
    }
}

// ---------------- attention + output, batched over all 10 t ----------------
__global__ __launch_bounds__(256, 2) void attn_kernel(
    const float* __restrict__ hdec,
    const float* __restrict__ projW, const float* __restrict__ proj_b,
    const float* __restrict__ projWT,
    const float* __restrict__ attn_WT, const float* __restrict__ attn_b,
    const float* __restrict__ out_WT, const float* __restrict__ out_b,
    const ushort_t* __restrict__ hs, float* __restrict__ out)
{
    const int b = blockIdx.x;
    const int tid = threadIdx.x;

    __shared__ __align__(16) float hd[1280];
    __shared__ __align__(16) float reg1[2560];
    __shared__ __align__(16) float sc[2560];
    __shared__ __align__(16) float part[10240];
    __shared__ __align__(16) float wsum[2560];

    const ushort_t* e = hs + (size_t)b * 65536;

    for (int i = tid; i < 1280; i += 256) hd[i] = hdec[(size_t)b * 1280 + i];
    __syncthreads();

    // phase 0: q[t][d] = sum_k hd[t][k] * projW[k][d]  (swizzle-stored)
    {
        float acc[10];
        #pragma unroll
        for (int t = 0; t < 10; ++t) acc[t] = 0.f;
        for (int k = 0; k < 128; ++k) {
            float pw = projW[k * 256 + tid];
            #pragma unroll
            for (int t = 0; t < 10; ++t) acc[t] = fmaf(hd[t * 128 + k], pw, acc[t]);
        }
        int swd = tid ^ ((((uint_t)tid >> 5) & 7) << 2);
        #pragma unroll
        for (int t = 0; t < 10; ++t) reg1[t * 256 + swd] = acc[t];
    }
    __syncthreads();

    // phase 1: scores[t][s] = e[s][:] . q[t][:]
    {
        const int w = tid >> 6, l = tid & 63;
        const int s3 = l >> 3, k8 = l & 7;
        for (int pass = 0; pass < 8; ++pass) {
            int s = w * 64 + pass * 8 + s3;
            const ushort_t* row = e + s * 256 + k8 * 32;
            uint4 e0 = *reinterpret_cast<const uint4*>(row);
            uint4 e1 = *reinterpret_cast<const uint4*>(row + 8);
            uint4 e2 = *reinterpret_cast<const uint4*>(row + 16);
            uint4 e3 = *reinterpret_cast<const uint4*>(row + 24);
            float acc[10];
            #pragma unroll
            for (int t = 0; t < 10; ++t) {
                const float* qb = &reg1[t * 256];
                float a = 0.f;
                #define QCH(i) (*reinterpret_cast<const float4*>(&qb[(k8 * 32 + (i) * 4) ^ (k8 << 2)]))
                #define DOT4(pa, pb, qv) { float4 q_ = (qv); \
                    a = fmaf(bflo(pa), q_.x, a); a = fmaf(bfhi(pa), q_.y, a); \
                    a = fmaf(bflo(pb), q_.z, a); a = fmaf(bfhi(pb), q_.w, a); }
                DOT4(e0.x, e0.y, QCH(0)); DOT4(e0.z, e0.w, QCH(1));
                DOT4(e1.x, e1.y, QCH(2)); DOT4(e1.z, e1.w, QCH(3));
                DOT4(e2.x, e2.y, QCH(4)); DOT4(e2.z, e2.w, QCH(5));
                DOT4(e3.x, e3.y, QCH(6)); DOT4(e3.z, e3.w, QCH(7));
                #undef QCH
                #undef DOT4
                acc[t] = a;
            }
            #pragma unroll
            for (int t = 0; t < 10; ++t) {
                acc[t] += __shfl_xor(acc[t], 1);
                acc[t] += __shfl_xor(acc[t], 2);
                acc[t] += __shfl_xor(acc[t], 4);
            }
            if (k8 == 0) {
                #pragma unroll
                for (int t = 0; t < 10; ++t) sc[t * 256 + s] = acc[t];
            }
        }
    }
    __syncthreads();

    // phase 2: softmax
    {
        const int w = tid >> 6, l = tid & 63;
        for (int t = w; t < 10; t += 4) {
            float4 sv = *reinterpret_cast<const float4*>(&sc[t * 256 + l * 4]);
            float m = fmaxf(fmaxf(sv.x, sv.y), fmaxf(sv.z, sv.w));
            #pragma unroll
            for (int o = 1; o < 64; o <<= 1) m = fmaxf(m, __shfl_xor(m, o));
            float e0 = fast_exp2((sv.x - m) * 1.4426950408889634f);
            float e1 = fast_exp2((sv.y - m) * 1.4426950408889634f);
            float e2 = fast_exp2((sv.z - m) * 1.4426950408889634f);
            float e3 = fast_exp2((sv.w - m) * 1.4426950408889634f);
            float ssum = e0 + e1 + e2 + e3;
            #pragma unroll
            for (int o = 1; o < 64; o <<= 1) ssum += __shfl_xor(ssum, o);
            float inv = fast_rcp(ssum);
            *reinterpret_cast<float4*>(&sc[t * 256 + l * 4]) =
                make_float4(e0 * inv, e1 * inv, e2 * inv, e3 * inv);
        }
    }
    __syncthreads();

    // phase 3: wsum partials
    {
        const int w = tid >> 6, l = tid & 63;
        float ax[10], ay[10], az[10], aw2[10];
        #pragma unroll
        for (int t = 0; t < 10; ++t) { ax[t] = 0.f; ay[t] = 0.f; az[t] = 0.f; aw2[t] = 0.f; }
        const ushort_t* col = e + l * 4;
        for (int s = w * 64; s < w * 64 + 64; ++s) {
            uint2 uu = *reinterpret_cast<const uint2*>(col + (size_t)s * 256);
            float v0 = bflo(uu.x), v1 = bfhi(uu.x), v2 = bflo(uu.y), v3 = bfhi(uu.y);
            #pragma unroll
            for (int t = 0; t < 10; ++t) {
                float awv = sc[t * 256 + s];
                ax[t] = fmaf(v0, awv, ax[t]); ay[t] = fmaf(v1, awv, ay[t]);
                az[t] = fmaf(v2, awv, az[t]); aw2[t] = fmaf(v3, awv, aw2[t]);
            }
        }
        #pragma unroll
        for (int t = 0; t < 10; ++t)
            *reinterpret_cast<float4*>(&part[(w * 10 + t) * 256 + l * 4]) =
                make_float4(ax[t], ay[t], az[t], aw2[t]);
    }
    __syncthreads();

    // phase 4: reduce partials
    for (int i = tid; i < 2560; i += 256)
        wsum[i] = part[i] + part[2560 + i] + part[5120 + i] + part[7680 + i];
    __syncthreads();

    // phase 5: ctx
    {
        const int u = tid & 127, th = tid >> 7;
        float acc[5];
        #pragma unroll
        for (int i = 0; i < 5; ++i) acc[i] = proj_b[u];
        for (int k = 0; k < 256; ++k) {
            float pw = projWT[k * 128 + u];
            #pragma unroll
            for (int i = 0; i < 5; ++i) acc[i] = fmaf(pw, wsum[(th * 5 + i) * 256 + k], acc[i]);
        }
        #pragma unroll
        for (int i = 0; i < 5; ++i) reg1[(th * 5 + i) * 128 + u] = acc[i];
    }
    __syncthreads();

    // phase 6: comb
    {
        const int u = tid & 127, th = tid >> 7;
        float acc[5];
        #pragma unroll
        for (int i = 0; i < 5; ++i) acc[i] = attn_b[u];
        for (int k = 0; k < 128; ++k) {
            float a1 = attn_WT[k * 128 + u];
            #pragma unroll
            for (int i = 0; i < 5; ++i) acc[i] = fmaf(a1, hd[(th * 5 + i) * 128 + k], acc[i]);
        }
        for (int k = 0; k < 128; ++k) {
            float a2 = attn_WT[(128 + k) * 128 + u];
            #pragma unroll
            for (int i = 0; i < 5; ++i) acc[i] = fmaf(a2, reg1[(th * 5 + i) * 128 + k], acc[i]);
        }
        #pragma unroll
        for (int i = 0; i < 5; ++i) reg1[1280 + (th * 5 + i) * 128 + u] = tanh_(acc[i]);
    }
    __syncthreads();

    // phase 7: logits
    for (int o = tid; o < 280; o += 256) {
        int t = o / 28, v = o - t * 28;
        float acc = out_b[v];
        #pragma unroll 4
        for (int k = 0; k < 128; ++k)
            acc = fmaf(out_WT[k * 28 + v], reg1[1280 + t * 128 + k], acc);
        out[(size_t)b * 280 + o] = acc;
    }
}

extern "C" void kernel_launch(void* const* d_in, const int* in_sizes, int n_in,
                              void* d_out, int out_size, void* d_ws, size_t ws_size,
                              hipStream_t stream) {
    const int* src      = (const int*)d_in[0];
    const int* target   = (const int*)d_in[1];
    const float* embed  = (const float*)d_in[2];
    const float* Wih_f  = (const float*)d_in[3];
    const float* Whh_f  = (const float*)d_in[4];
    const float* b_f    = (const float*)d_in[5];
    const float* Wih_b  = (const float*)d_in[6];
    const float* Whh_b  = (const float*)d_in[7];
    const float* b_b    = (const float*)d_in[8];
    const float* Wih_d  = (const float*)d_in[9];
    const float* Whh_d  = (const float*)d_in[10];
    const float* b_d    = (const float*)d_in[11];
    const float* proj_W = (const float*)d_in[12];
    const float* proj_b = (const float*)d_in[13];
    const float* attn_W = (const float*)d_in[14];
    const float* attn_b = (const float*)d_in[15];
    const float* out_W  = (const float*)d_in[16];
    const float* out_b  = (const float*)d_in[17];

    float* ws = (float*)d_ws;
    ushort_t* hs = (ushort_t*)((char*)d_ws + HS_BYTE_OFF);
    float* out = (float*)d_out;

    prep_kernel<<<(PREP_N + 255) / 256, 256, 0, stream>>>(
        embed, Wih_f, b_f, Wih_b, b_b, Wih_d, b_d,
        Whh_f, Whh_b, Whh_d, attn_W, out_W, proj_W, ws);

    enc_kernel<<<256, 512, 0, stream>>>(
        src, ws + XTG, (const ushort_t*)(ws + WPK),
        ws + HFIN, ws + CFIN, hs);

    dec_lstm_kernel<<<256, 512, 0, stream>>>(
        target, ws + XTD, ws + WTD, ws + HFIN, ws + CFIN, ws + HDEC);

    attn_kernel<<<512, 256, 0, stream>>>(
        ws + HDEC, proj_W, proj_b, ws + PWT, ws + AWT, attn_b,
        ws + OWT, out_b, hs, out);
}

// Round 12
// 319.430 us; speedup vs baseline: 1.8073x; 1.0880x over previous
//
#include <hip/hip_runtime.h>
#include <hip/hip_bf16.h>
#include <stdint.h>

typedef unsigned short ushort_t;
typedef unsigned int uint_t;
typedef __attribute__((ext_vector_type(8))) short bfrag;   // 8 bf16 = 4 VGPR
typedef __attribute__((ext_vector_type(4))) float f32x4;

#define B_ 512
#define S_ 256
#define T_ 10
#define V_ 28
#define H_ 128

// ---- workspace layout (float element offsets) ----
#define XTD 0         // dec xg table [28][512]
#define XTG 14336     // enc xg gate-interleaved [2][28][128][4]
#define WTD 43008     // dec WhhT [128][512]
#define AWT 108544    // attn_WT [256][128]
#define OWT 141312    // out_WT [128][28]
#define PWT 144896    // projWT [256][128]
#define WPK 177664    // enc W_hi bf16 frag pack, 131072 ushort (K=128)
#define HFIN 308736
#define CFIN 439808
#define HDEC 570880
#define HS_BYTE_OFF (1226240ull * 4ull)
#define PREP_N 308736

__device__ __forceinline__ float fast_exp2(float x) { return __builtin_amdgcn_exp2f(x); }
__device__ __forceinline__ float fast_rcp(float x)  { return __builtin_amdgcn_rcpf(x); }
__device__ __forceinline__ float sigm(float x) {
    return fast_rcp(1.f + fast_exp2(-1.4426950408889634f * x));
}
__device__ __forceinline__ float tanh_(float x) {
    return 1.f - 2.f * fast_rcp(1.f + fast_exp2(2.8853900817779268f * x));
}
__device__ __forceinline__ ushort_t f2bf(float x) {
    uint_t u = __float_as_uint(x);
    return (ushort_t)((u + 0x7FFFu + ((u >> 16) & 1u)) >> 16);  // RNE
}
__device__ __forceinline__ float bflo(uint_t u) { return __uint_as_float(u << 16); }
__device__ __forceinline__ float bfhi(uint_t u) { return __uint_as_float(u & 0xFFFF0000u); }

// LDS-only barrier: drain LDS ops, sync, fence scheduler (rule #18).
__device__ __forceinline__ void lds_barrier() {
    asm volatile("s_waitcnt lgkmcnt(0)" ::: "memory");
    __builtin_amdgcn_s_barrier();
    __builtin_amdgcn_sched_barrier(0);
}

// ---------------- prep ----------------
__global__ __launch_bounds__(256) void prep_kernel(
    const float* __restrict__ embed,
    const float* __restrict__ Wih_f, const float* __restrict__ b_f,
    const float* __restrict__ Wih_b, const float* __restrict__ b_b,
    const float* __restrict__ Wih_d, const float* __restrict__ b_d,
    const float* __restrict__ Whh_f, const float* __restrict__ Whh_b,
    const float* __restrict__ Whh_d,
    const float* __restrict__ attn_W, const float* __restrict__ out_W,
    const float* __restrict__ proj_W,
    float* __restrict__ ws)
{
    int i = blockIdx.x * 256 + threadIdx.x;
    if (i < XTG) {                         // dec xg table: [v][j]
        int v = i >> 9, jj = i & 511;
        float acc = b_d[jj];
        #pragma unroll
        for (int e = 0; e < 32; ++e) acc = fmaf(embed[v * 32 + e], Wih_d[jj * 32 + e], acc);
        ws[XTD + i] = acc;
    } else if (i < WTD) {                  // enc xg gate-interleaved: [d][v][u][g]
        int r = i - XTG; int d = r / 14336; int rem = r % 14336;
        int v = rem >> 9, q = rem & 511;
        int uu = q >> 2, g = q & 3;
        int jj = g * 128 + uu;
        const float* Wih = d ? Wih_b : Wih_f;
        const float* bb  = d ? b_b   : b_f;
        float acc = bb[jj];
        #pragma unroll
        for (int e = 0; e < 32; ++e) acc = fmaf(embed[v * 32 + e], Wih[jj * 32 + e], acc);
        ws[XTG + r] = acc;
    } else if (i < AWT) {                  // dec WhhT[k][j]
        int r = i - WTD; int k = r >> 9, jj = r & 511;
        ws[WTD + r] = Whh_d[jj * 128 + k];
    } else if (i < OWT) {                  // attn_WT[k][u]
        int r = i - AWT; int k = r >> 7, uu = r & 127;
        ws[i] = attn_W[uu * 256 + k];
    } else if (i < PWT) {                  // out_WT[k][v]
        int r = i - OWT; int k = r / 28, v = r % 28;
        ws[i] = out_W[v * 128 + k];
    } else if (i < WPK) {                  // projWT[k][u]
        int r = i - PWT; int k = r >> 7, uu = r & 127;
        ws[i] = proj_W[uu * 256 + k];
    } else if (i < PREP_N) {               // enc W_hi frag pack, K=128 (pure bf16 hi)
        int i2 = (i - WPK) * 2;            // 2 ushorts per thread
        #pragma unroll
        for (int p = 0; p < 2; ++p, ++i2) {
            int e  = i2 & 7;
            int ll = (i2 >> 3) & 63;
            int kt = (i2 >> 9) & 3;
            int ni = (i2 >> 11) & 3;
            int wv = (i2 >> 13) & 7;
            int d  = (i2 >> 16) & 1;
            int jj = (ni * 8 + wv) * 16 + (ll & 15);   // gate column (N)
            int kp = kt * 32 + ((ll >> 4) << 3) + e;   // K index 0..127
            const float* Whh = d ? Whh_b : Whh_f;
            ((ushort_t*)(ws + WPK))[i2] = f2bf(Whh[jj * 128 + kp]);
        }
    }
}

// ---------------- encoder: MFMA K=128 bf16, rows at M={0,4,8,12}, in-lane cell ----------------
__global__ __launch_bounds__(512, 2) void enc_kernel(
    const int* __restrict__ src,
    const float* __restrict__ xtg_base,     // ws+XTG
    const ushort_t* __restrict__ wpk,       // ws+WPK
    float* __restrict__ hfin, float* __restrict__ cfin,
    ushort_t* __restrict__ hs)
{
    const int bx = blockIdx.x;
    const int dir = bx >> 7;
    const int b0 = (bx & 127) << 2;
    const int tid = threadIdx.x;
    const int w = tid >> 6, l = tid & 63;
    const int lg = l >> 4, col = l & 15;
    const int u = (w << 4) + col;          // 0..127: this lane's hidden unit
    const int row = lg;                    // this lane's batch row (cell owner)

    __shared__ __align__(16) ushort_t hb[2][4][144];   // [buf][row][swizzled u], stride-padded
    __shared__ __align__(16) int tokl[256][4];         // [s][row]

    for (int i = tid; i < 1024; i += 512)
        tokl[i >> 2][i & 3] = src[(b0 + (i & 3)) * S_ + (i >> 2)];
    for (int i = tid; i < 576; i += 512) ((uint_t*)hb)[i] = 0u;

    const float* xtg = xtg_base + dir * 14336;

    // persistent B fragments: 4 N-tiles x 4 K-tiles = 64 regs
    bfrag bf[4][4];
    {
        const ushort_t* wb = wpk + (((size_t)dir * 8 + w) << 13) + l * 8;
        #pragma unroll
        for (int ni = 0; ni < 4; ++ni)
            #pragma unroll
            for (int kt = 0; kt < 4; ++kt)
                bf[ni][kt] = *reinterpret_cast<const bfrag*>(wb + ((ni * 4 + kt) << 9));
    }
    __syncthreads();

    float c_reg = 0.f, h_reg = 0.f;

    f32x4 xgc;                              // this lane's 4 gate-bias terms for (row, u)
    {
        int p0 = dir ? (S_ - 1) : 0;
        xgc = *reinterpret_cast<const f32x4*>(xtg + ((size_t)tokl[p0][row] << 9) + (u << 2));
    }

    // A fragments: A row = lane&15; real rows at M = {0,4,8,12}
    const bfrag zf = {0, 0, 0, 0, 0, 0, 0, 0};
    bfrag af0 = zf, af1 = zf, af2 = zf, af3 = zf;
    const bool ard = ((col & 3) == 0);
    const int ar = col >> 2;               // A-read row
    const int swz = ar << 3;

    for (int t = 0; t < S_; ++t) {
        const int cb = t & 1, nb = cb ^ 1;

        // acc init: reg 0 = xg for (row, u); regs 1..3 are padding rows (stay 0)
        f32x4 a0 = {xgc[0], 0.f, 0.f, 0.f};
        f32x4 a1 = {xgc[1], 0.f, 0.f, 0.f};
        f32x4 a2 = {xgc[2], 0.f, 0.f, 0.f};
        f32x4 a3 = {xgc[3], 0.f, 0.f, 0.f};

        // prefetch next step's xg (1 load/lane, consumed next iteration)
        if (t + 1 < S_) {
            int pn = dir ? (S_ - 2 - t) : (t + 1);
            xgc = *reinterpret_cast<const f32x4*>(xtg + ((size_t)tokl[pn][row] << 9) + (u << 2));
        }

        // masked A-frag reads: lanes col in {0,4,8,12}, XOR-swizzled
        if (ard) {
            const ushort_t* hp = &hb[cb][ar][0];
            af0 = *reinterpret_cast<const bfrag*>(hp + ((  0 + (lg << 3)) ^ swz));
            af1 = *reinterpret_cast<const bfrag*>(hp + (( 32 + (lg << 3)) ^ swz));
            af2 = *reinterpret_cast<const bfrag*>(hp + (( 64 + (lg << 3)) ^ swz));
            af3 = *reinterpret_cast<const bfrag*>(hp + (( 96 + (lg << 3)) ^ swz));
        }

        #define KT1(AF, kt) { \
            a0 = __builtin_amdgcn_mfma_f32_16x16x32_bf16(AF, bf[0][kt], a0, 0, 0, 0); \
            a1 = __builtin_amdgcn_mfma_f32_16x16x32_bf16(AF, bf[1][kt], a1, 0, 0, 0); \
            a2 = __builtin_amdgcn_mfma_f32_16x16x32_bf16(AF, bf[2][kt], a2, 0, 0, 0); \
            a3 = __builtin_amdgcn_mfma_f32_16x16x32_bf16(AF, bf[3][kt], a3, 0, 0, 0); \
        }
        KT1(af0, 0) KT1(af1, 1) KT1(af2, 2) KT1(af3, 3)
        #undef KT1

        // cell: fully in-register, every lane owns one (row, u)
        {
            float gi = a0[0], gf = a1[0], gg = a2[0], go = a3[0];
            float ii = sigm(gi), ff = sigm(gf), gG = tanh_(gg), oo = sigm(go);
            c_reg = ff * c_reg + ii * gG;
            float h = oo * tanh_(c_reg);
            h_reg = h;
            ushort_t hi = f2bf(h);
            hb[nb][row][u ^ (row << 3)] = hi;
            int pos = dir ? (S_ - 1 - t) : t;
            hs[((size_t)(b0 + row) * S_ + pos) * 256 + dir * 128 + u] = hi;
        }
        lds_barrier();
    }

    hfin[dir * 65536 + (b0 + row) * 128 + u] = h_reg;
    cfin[dir * 65536 + (b0 + row) * 128 + u] = c_reg;
}

// ---------------- decoder LSTM only: 10 steps, store hdec[b][t][128] ----------------
__global__ __launch_bounds__(512, 1) void dec_lstm_kernel(
    const int* __restrict__ target,
    const float* __restrict__ xt_d,
    const float* __restrict__ WhhT_d,
    const float* __restrict__ hfin, const float* __restrict__ cfin,
    float* __restrict__ hdec)
{
    const int b0 = blockIdx.x * 2;
    const int tid = threadIdx.x;
    const int j = tid;

    __shared__ __align__(16) float h_lds[2][128];
    __shared__ __align__(16) float g_lds[2][512];

    float4 w4[32];
    #pragma unroll
    for (int kc = 0; kc < 32; ++kc) {
        w4[kc].x = WhhT_d[(kc * 4 + 0) * 512 + j];
        w4[kc].y = WhhT_d[(kc * 4 + 1) * 512 + j];
        w4[kc].z = WhhT_d[(kc * 4 + 2) * 512 + j];
        w4[kc].w = WhhT_d[(kc * 4 + 3) * 512 + j];
    }
    const int r1 = tid >> 7, u1 = tid & 127;
    float c = 0.f;
    if (tid < 256) {
        int b = b0 + r1;
        c = cfin[b * 128 + u1] + cfin[65536 + b * 128 + u1];
        h_lds[r1][u1] = hfin[b * 128 + u1] + hfin[65536 + b * 128 + u1];
    }
    __syncthreads();

    for (int t = 0; t < T_; ++t) {
        int tok0 = (t == 0) ? 0 : target[(b0 + 0) * T_ + t - 1];
        int tok1 = (t == 0) ? 0 : target[(b0 + 1) * T_ + t - 1];
        float a0 = xt_d[tok0 * 512 + j];
        float a1 = xt_d[tok1 * 512 + j];
        #pragma unroll
        for (int kc = 0; kc < 32; ++kc) {
            const float4 w = w4[kc];
            const float4 h0 = *reinterpret_cast<const float4*>(&h_lds[0][kc * 4]);
            const float4 h1 = *reinterpret_cast<const float4*>(&h_lds[1][kc * 4]);
            a0 = fmaf(h0.x, w.x, a0); a0 = fmaf(h0.y, w.y, a0); a0 = fmaf(h0.z, w.z, a0); a0 = fmaf(h0.w, w.w, a0);
            a1 = fmaf(h1.x, w.x, a1); a1 = fmaf(h1.y, w.y, a1); a1 = fmaf(h1.z, w.z, a1); a1 = fmaf(h1.w, w.w, a1);
        }
        g_lds[0][j] = a0; g_lds[1][j] = a1;
        __syncthreads();
        if (tid < 256) {
            float gi = g_lds[r1][u1], gf = g_lds[r1][u1 + 128];
            float gg = g_lds[r1][u1 + 256], go = g_lds[r1][u1 + 384];
            float ii = sigm(gi), ff = sigm(gf), g_ = tanh_(gg), oo = sigm(go);
            c = ff * c + ii * g_;
            float h = oo * tanh_(c);
            h_lds[r1][u1] = h;
            hdec[((size_t)(b0 + r1) * T_ + t) * 128 + u1] = h;
        }
        __syncthreads();
    }
}

// ---------------- attention + output, batched over all 10 t ----------------
// e staged into LDS during phase 1 (write-through); phase 3 reads LDS.
// part/wsum alias the dead e region after phase 3. 155 KB LDS, 1 block/CU.
#define ELDS_STRIDE 260   // ushorts per row (520B, 8B-aligned rows, bank-spread)
__global__ __launch_bounds__(256, 1) void attn_kernel(
    const float* __restrict__ hdec,
    const float* __restrict__ projW, const float* __restrict__ proj_b,
    const float* __restrict__ projWT,
    const float* __restrict__ attn_WT, const float* __restrict__ attn_b,
    const float* __restrict__ out_WT, const float* __restrict__ out_b,
    const ushort_t* __restrict__ hs, float* __restrict__ out)
{
    const int b = blockIdx.x;
    const int tid = threadIdx.x;

    __shared__ __align__(16) char smem[158720];
    ushort_t* e_lds = (ushort_t*)smem;                    // [256][260] = 133120 B
    float* hd   = (float*)(smem + 133120);                // [10][128]  = 5120 B
    float* reg1 = (float*)(smem + 138240);                // [2560]     = 10240 B
    float* sc   = (float*)(smem + 148480);                // [2560]     = 10240 B
    float* part = (float*)smem;                           // alias (phase>=3b): [4][10][256] = 40960 B
    float* wsum = (float*)(smem + 40960);                 // alias: [2560] = 10240 B

    const ushort_t* e = hs + (size_t)b * 65536;

    for (int i = tid; i < 1280; i += 256) hd[i] = hdec[(size_t)b * 1280 + i];
    __syncthreads();

    // phase 0: q[t][d] = sum_k hd[t][k] * projW[k][d]  (swizzle-stored)
    {
        float acc[10];
        #pragma unroll
        for (int t = 0; t < 10; ++t) acc[t] = 0.f;
        for (int k = 0; k < 128; ++k) {
            float pw = projW[k * 256 + tid];
            #pragma unroll
            for (int t = 0; t < 10; ++t) acc[t] = fmaf(hd[t * 128 + k], pw, acc[t]);
        }
        int swd = tid ^ ((((uint_t)tid >> 5) & 7) << 2);
        #pragma unroll
        for (int t = 0; t < 10; ++t) reg1[t * 256 + swd] = acc[t];
    }
    __syncthreads();

    // phase 1: scores[t][s] = e[s][:] . q[t][:]  -- global stream with prefetch,
    //          write-through staging into e_lds.
    {
        const int w = tid >> 6, l = tid & 63;
        const int s3 = l >> 3, k8 = l & 7;
        const ushort_t* row0 = e + (w * 64 + s3) * 256 + k8 * 32;
        uint4 e0 = *reinterpret_cast<const uint4*>(row0);
        uint4 e1 = *reinterpret_cast<const uint4*>(row0 + 8);
        uint4 e2 = *reinterpret_cast<const uint4*>(row0 + 16);
        uint4 e3 = *reinterpret_cast<const uint4*>(row0 + 24);
        for (int pass = 0; pass < 8; ++pass) {
            int s = w * 64 + pass * 8 + s3;
            uint4 f0, f1, f2, f3;
            if (pass + 1 < 8) {
                const ushort_t* nrow = e + (s + 8) * 256 + k8 * 32;
                f0 = *reinterpret_cast<const uint4*>(nrow);
                f1 = *reinterpret_cast<const uint4*>(nrow + 8);
                f2 = *reinterpret_cast<const uint4*>(nrow + 16);
                f3 = *reinterpret_cast<const uint4*>(nrow + 24);
            }
            // stage to LDS (8B-aligned uint2 stores)
            {
                ushort_t* lr = e_lds + s * ELDS_STRIDE + k8 * 32;
                *reinterpret_cast<uint2*>(lr + 0)  = make_uint2(e0.x, e0.y);
                *reinterpret_cast<uint2*>(lr + 4)  = make_uint2(e0.z, e0.w);
                *reinterpret_cast<uint2*>(lr + 8)  = make_uint2(e1.x, e1.y);
                *reinterpret_cast<uint2*>(lr + 12) = make_uint2(e1.z, e1.w);
                *reinterpret_cast<uint2*>(lr + 16) = make_uint2(e2.x, e2.y);
                *reinterpret_cast<uint2*>(lr + 20) = make_uint2(e2.z, e2.w);
                *reinterpret_cast<uint2*>(lr + 24) = make_uint2(e3.x, e3.y);
                *reinterpret_cast<uint2*>(lr + 28) = make_uint2(e3.z, e3.w);
            }
            float acc[10];
            #pragma unroll
            for (int t = 0; t < 10; ++t) {
                const float* qb = &reg1[t * 256];
                float a = 0.f;
                #define QCH(i) (*reinterpret_cast<const float4*>(&qb[(k8 * 32 + (i) * 4) ^ (k8 << 2)]))
                #define DOT4(pa, pb, qv) { float4 q_ = (qv); \
                    a = fmaf(bflo(pa), q_.x, a); a = fmaf(bfhi(pa), q_.y, a); \
                    a = fmaf(bflo(pb), q_.z, a); a = fmaf(bfhi(pb), q_.w, a); }
                DOT4(e0.x, e0.y, QCH(0)); DOT4(e0.z, e0.w, QCH(1));
                DOT4(e1.x, e1.y, QCH(2)); DOT4(e1.z, e1.w, QCH(3));
                DOT4(e2.x, e2.y, QCH(4)); DOT4(e2.z, e2.w, QCH(5));
                DOT4(e3.x, e3.y, QCH(6)); DOT4(e3.z, e3.w, QCH(7));
                #undef QCH
                #undef DOT4
                acc[t] = a;
            }
            #pragma unroll
            for (int t = 0; t < 10; ++t) {
                acc[t] += __shfl_xor(acc[t], 1);
                acc[t] += __shfl_xor(acc[t], 2);
                acc[t] += __shfl_xor(acc[t], 4);
            }
            if (k8 == 0) {
                #pragma unroll
                for (int t = 0; t < 10; ++t) sc[t * 256 + s] = acc[t];
            }
            e0 = f0; e1 = f1; e2 = f2; e3 = f3;
        }
    }
    __syncthreads();

    // phase 2: softmax
    {
        const int w = tid >> 6, l = tid & 63;
        for (int t = w; t < 10; t += 4) {
            float4 sv = *reinterpret_cast<const float4*>(&sc[t * 256 + l * 4]);
            float m = fmaxf(fmaxf(sv.x, sv.y), fmaxf(sv.z, sv.w));
            #pragma unroll
            for (int o = 1; o < 64; o <<= 1) m = fmaxf(m, __shfl_xor(m, o));
            float e0 = fast_exp2((sv.x - m) * 1.4426950408889634f);
            float e1 = fast_exp2((sv.y - m) * 1.4426950408889634f);
            float e2 = fast_exp2((sv.z - m) * 1.4426950408889634f);
            float e3 = fast_exp2((sv.w - m) * 1.4426950408889634f);
            float ssum = e0 + e1 + e2 + e3;
            #pragma unroll
            for (int o = 1; o < 64; o <<= 1) ssum += __shfl_xor(ssum, o);
            float inv = fast_rcp(ssum);
            *reinterpret_cast<float4*>(&sc[t * 256 + l * 4]) =
                make_float4(e0 * inv, e1 * inv, e2 * inv, e3 * inv);
        }
    }
    __syncthreads();

    // phase 3: wsum partials -- e read from LDS now (short latency)
    {
        const int w = tid >> 6, l = tid & 63;
        float ax[10], ay[10], az[10], aw2[10];
        #pragma unroll
        for (int t = 0; t < 10; ++t) { ax[t] = 0.f; ay[t] = 0.f; az[t] = 0.f; aw2[t] = 0.f; }
        const ushort_t* col = e_lds + l * 4;
        for (int s = w * 64; s < w * 64 + 64; ++s) {
            uint2 uu = *reinterpret_cast<const uint2*>(col + s * ELDS_STRIDE);
            float v0 = bflo(uu.x), v1 = bfhi(uu.x), v2 = bflo(uu.y), v3 = bfhi(uu.y);
            #pragma unroll
            for (int t = 0; t < 10; ++t) {
                float awv = sc[t * 256 + s];
                ax[t] = fmaf(v0, awv, ax[t]); ay[t] = fmaf(v1, awv, ay[t]);
                az[t] = fmaf(v2, awv, az[t]); aw2[t] = fmaf(v3, awv, aw2[t]);
            }
        }
        __syncthreads();   // all e_lds reads complete before aliasing writes
        #pragma unroll
        for (int t = 0; t < 10; ++t)
            *reinterpret_cast<float4*>(&part[(w * 10 + t) * 256 + l * 4]) =
                make_float4(ax[t], ay[t], az[t], aw2[t]);
    }
    __syncthreads();

    // phase 4: reduce partials
    for (int i = tid; i < 2560; i += 256)
        wsum[i] = part[i] + part[2560 + i] + part[5120 + i] + part[7680 + i];
    __syncthreads();

    // phase 5: ctx
    {
        const int u = tid & 127, th = tid >> 7;
        float acc[5];
        #pragma unroll
        for (int i = 0; i < 5; ++i) acc[i] = proj_b[u];
        for (int k = 0; k < 256; ++k) {
            float pw = projWT[k * 128 + u];
            #pragma unroll
            for (int i = 0; i < 5; ++i) acc[i] = fmaf(pw, wsum[(th * 5 + i) * 256 + k], acc[i]);
        }
        #pragma unroll
        for (int i = 0; i < 5; ++i) reg1[(th * 5 + i) * 128 + u] = acc[i];
    }
    __syncthreads();

    // phase 6: comb
    {
        const int u = tid & 127, th = tid >> 7;
        float acc[5];
        #pragma unroll
        for (int i = 0; i < 5; ++i) acc[i] = attn_b[u];
        for (int k = 0; k < 128; ++k) {
            float a1 = attn_WT[k * 128 + u];
            #pragma unroll
            for (int i = 0; i < 5; ++i) acc[i] = fmaf(a1, hd[(th * 5 + i) * 128 + k], acc[i]);
        }
        for (int k = 0; k < 128; ++k) {
            float a2 = attn_WT[(128 + k) * 128 + u];
            #pragma unroll
            for (int i = 0; i < 5; ++i) acc[i] = fmaf(a2, reg1[(th * 5 + i) * 128 + k], acc[i]);
        }
        #pragma unroll
        for (int i = 0; i < 5; ++i) reg1[1280 + (th * 5 + i) * 128 + u] = tanh_(acc[i]);
    }
    __syncthreads();

    // phase 7: logits
    for (int o = tid; o < 280; o += 256) {
        int t = o / 28, v = o - t * 28;
        float acc = out_b[v];
        #pragma unroll 4
        for (int k = 0; k < 128; ++k)
            acc = fmaf(out_WT[k * 28 + v], reg1[1280 + t * 128 + k], acc);
        out[(size_t)b * 280 + o] = acc;
    }
}

extern "C" void kernel_launch(void* const* d_in, const int* in_sizes, int n_in,
                              void* d_out, int out_size, void* d_ws, size_t ws_size,
                              hipStream_t stream) {
    const int* src      = (const int*)d_in[0];
    const int* target   = (const int*)d_in[1];
    const float* embed  = (const float*)d_in[2];
    const float* Wih_f  = (const float*)d_in[3];
    const float* Whh_f  = (const float*)d_in[4];
    const float* b_f    = (const float*)d_in[5];
    const float* Wih_b  = (const float*)d_in[6];
    const float* Whh_b  = (const float*)d_in[7];
    const float* b_b    = (const float*)d_in[8];
    const float* Wih_d  = (const float*)d_in[9];
    const float* Whh_d  = (const float*)d_in[10];
    const float* b_d    = (const float*)d_in[11];
    const float* proj_W = (const float*)d_in[12];
    const float* proj_b = (const float*)d_in[13];
    const float* attn_W = (const float*)d_in[14];
    const float* attn_b = (const float*)d_in[15];
    const float* out_W  = (const float*)d_in[16];
    const float* out_b  = (const float*)d_in[17];

    float* ws = (float*)d_ws;
    ushort_t* hs = (ushort_t*)((char*)d_ws + HS_BYTE_OFF);
    float* out = (float*)d_out;

    prep_kernel<<<(PREP_N + 255) / 256, 256, 0, stream>>>(
        embed, Wih_f, b_f, Wih_b, b_b, Wih_d, b_d,
        Whh_f, Whh_b, Whh_d, attn_W, out_W, proj_W, ws);

    enc_kernel<<<256, 512, 0, stream>>>(
        src, ws + XTG, (const ushort_t*)(ws + WPK),
        ws + HFIN, ws + CFIN, hs);

    dec_lstm_kernel<<<256, 512, 0, stream>>>(
        target, ws + XTD, ws + WTD, ws + HFIN, ws + CFIN, ws + HDEC);

    attn_kernel<<<512, 256, 0, stream>>>(
        ws + HDEC, proj_W, proj_b, ws + PWT, ws + AWT, attn_b,
        ws + OWT, out_b, hs, out);
}